// Round 11
// baseline (632.324 us; speedup 1.0000x reference)
//
#include <hip/hip_runtime.h>
#include <cstdint>
#include <cmath>

#define BN_ 4
#define NPTS 2048
#define KNB 20
#define TOTP (BN_ * NPTS)   // 8192

typedef unsigned short u16;
typedef unsigned long long u64;
typedef short bf16x8 __attribute__((ext_vector_type(8)));
typedef u16 u16x8 __attribute__((ext_vector_type(8)));
typedef float f32x4 __attribute__((ext_vector_type(4)));

// ---------------- transpose x (B,3,N) -> P0 (B*N, 3)
__global__ void k_transpose(const float* __restrict__ x, float* __restrict__ P0) {
  int i = blockIdx.x * 256 + threadIdx.x;
  if (i >= TOTP) return;
  int b = i / NPTS, n = i % NPTS;
#pragma unroll
  for (int c = 0; c < 3; ++c)
    P0[i * 3 + c] = x[((size_t)b * 3 + c) * NPTS + n];
}

// ---------------- squared norms per point
__global__ void k_sqnorm(const float* __restrict__ base, int ld, int C, float* __restrict__ xx) {
  int i = blockIdx.x * 256 + threadIdx.x;
  if (i >= TOTP) return;
  const float* r = base + (size_t)i * ld;
  float s = 0.f;
  for (int c = 0; c < C; ++c) s = fmaf(r[c], r[c], s);
  xx[i] = s;
}

// ======================================================================
// Symmetric Gram: 64x64 tiles, __launch_bounds__(256,4).  (R10 proven:
// LDS-transposed mirror write -> contiguous 256B rows.)
// ======================================================================
__global__ __launch_bounds__(256, 4) void k_gram64(const float* __restrict__ A_all, int lda,
                                                   int K, float* __restrict__ G4) {
  __shared__ float As[2][8][64];
  __shared__ float Bs[2][8][64];
  __shared__ float tb[64][68];  // [col_local][row_local], row stride 272B (16B-aligned)
  const int T = NPTS / 64;  // 32
  int q = blockIdx.x;
  int bi = 0;
  while (q >= T - bi) { q -= T - bi; ++bi; }
  int bj = bi + q;
  int b = blockIdx.z;
  const float* A = A_all + (size_t)b * NPTS * lda;
  float* G = G4 + (size_t)b * NPTS * NPTS;
  int tid = threadIdx.x;
  int i0 = bi * 64, m0 = bj * 64;
  int tx = tid & 15, ty = tid >> 4;
  int lr = tid >> 2;          // 0..63
  int lc = (tid & 3) * 2;     // 0,2,4,6
  const float* Arow = A + (size_t)(i0 + lr) * lda;
  const float* Brow = A + (size_t)(m0 + lr) * lda;
  float acc[4][4] = {};
  float2 pa, pb;

  pa = *(const float2*)(Arow + lc);
  pb = *(const float2*)(Brow + lc);
  As[0][lc + 0][lr] = pa.x; As[0][lc + 1][lr] = pa.y;
  Bs[0][lc + 0][lr] = pb.x; Bs[0][lc + 1][lr] = pb.y;
  __syncthreads();
  for (int k0 = 0; k0 < K; k0 += 8) {
    int cur = (k0 >> 3) & 1;
    bool more = (k0 + 8 < K);
    if (more) {
      pa = *(const float2*)(Arow + k0 + 8 + lc);
      pb = *(const float2*)(Brow + k0 + 8 + lc);
    }
#pragma unroll
    for (int k = 0; k < 8; ++k) {
      float4 a0 = *(const float4*)&As[cur][k][ty * 4];
      float4 b0 = *(const float4*)&Bs[cur][k][tx * 4];
      float ar[4] = {a0.x, a0.y, a0.z, a0.w};
      float br[4] = {b0.x, b0.y, b0.z, b0.w};
#pragma unroll
      for (int ii = 0; ii < 4; ++ii)
#pragma unroll
        for (int jj = 0; jj < 4; ++jj)
          acc[ii][jj] = fmaf(ar[ii], br[jj], acc[ii][jj]);
    }
    if (more) {
      int nxt = cur ^ 1;
      As[nxt][lc + 0][lr] = pa.x; As[nxt][lc + 1][lr] = pa.y;
      Bs[nxt][lc + 0][lr] = pb.x; Bs[nxt][lc + 1][lr] = pb.y;
    }
    __syncthreads();
  }
#pragma unroll
  for (int ii = 0; ii < 4; ++ii) {
    int row = i0 + ty * 4 + ii;
    float4 vv = {acc[ii][0], acc[ii][1], acc[ii][2], acc[ii][3]};
    *(float4*)(G + (size_t)row * NPTS + m0 + tx * 4) = vv;
  }
  if (bi != bj) {
    // stage transposed: tb[col_local][row_local] = acc[row_l][col_l]
#pragma unroll
    for (int jj = 0; jj < 4; ++jj) {
      float4 vv = {acc[0][jj], acc[1][jj], acc[2][jj], acc[3][jj]};
      *(float4*)&tb[tx * 4 + jj][ty * 4] = vv;
    }
    __syncthreads();
    int cl0 = tid >> 4;        // 0..15
    int cc = (tid & 15) * 4;   // 0..60
#pragma unroll
    for (int qq = 0; qq < 4; ++qq) {
      int cl = qq * 16 + cl0;
      float4 vv = *(const float4*)&tb[cl][cc];
      *(float4*)(G + (size_t)(m0 + cl) * NPTS + i0 + cc) = vv;  // 256B-contig rows
    }
  }
}

// ======================================================================
// Final GEMM via split-bf16 (hi/lo) 3-pass MFMA (R0 proven).
// ======================================================================

__device__ __forceinline__ u16 bf16_rn(float f) {
  unsigned u = __float_as_uint(f);
  unsigned r = u + 0x7fffu + ((u >> 16) & 1u);
  return (u16)(r >> 16);
}

// one thread per 8-element k-chunk; src is row-major [rows][512]
__global__ __launch_bounds__(256) void k_split_swz(const float* __restrict__ src,
                                                   u16* __restrict__ dh,
                                                   u16* __restrict__ dl) {
  int c = blockIdx.x * 256 + threadIdx.x;
  int row = c >> 6;            // 64 chunks per row (512/8)
  int k0 = (c & 63) << 3;      // 0..504
  const float4* s = (const float4*)(src + (size_t)row * 512 + k0);
  float4 v0 = s[0], v1 = s[1];
  float vv[8] = {v0.x, v0.y, v0.z, v0.w, v1.x, v1.y, v1.z, v1.w};
  u16x8 hv, lv;
#pragma unroll
  for (int e = 0; e < 8; ++e) {
    u16 h = bf16_rn(vv[e]);
    float fh = __uint_as_float((unsigned)h << 16);
    hv[e] = h;
    lv[e] = bf16_rn(vv[e] - fh);
  }
  int tr = row >> 7, rloc = row & 127, tk = k0 >> 5, ss = (k0 >> 3) & 3;
  size_t tb = ((size_t)(tr * 16 + tk)) * 4096;  // tile base in u16 units (8KB)
  unsigned P = ((unsigned)(rloc * 64 + ss * 16)) ^ (((unsigned)(rloc & 7)) << 4);
  *(u16x8*)(dh + tb + (P >> 1)) = hv;
  *(u16x8*)(dl + tb + (P >> 1)) = lv;
}

__device__ __forceinline__ void gl2lds16(const void* g, void* l) {
  __builtin_amdgcn_global_load_lds(
      (const __attribute__((address_space(1))) unsigned int*)g,
      (__attribute__((address_space(3))) unsigned int*)l, 16, 0, 0);
}

#define MFMA16(A, B, C) __builtin_amdgcn_mfma_f32_16x16x32_bf16(A, B, C, 0, 0, 0)

__global__ __launch_bounds__(256, 2) void k_gemm_mfma(
    const u16* __restrict__ AhT, const u16* __restrict__ AlT,
    const u16* __restrict__ BhT, const u16* __restrict__ BlT,
    float* __restrict__ Cout) {
  // block: 128x128 tile; 4 waves, each 64x64 (4x4 frags of 16x16); BK=32
  __shared__ u16 lds[2][4][4096];  // [buf][Ah,Al,Bh,Bl][8KB tile]  = 64 KB
  int tid = threadIdx.x;
  int w = tid >> 6, lane = tid & 63;
  int wr = w >> 1, wc = w & 1;
  int fr = lane & 15, fs = lane >> 4;

  size_t tbA = (size_t)blockIdx.y * 16 * 4096;  // u16 units
  size_t tbB = (size_t)blockIdx.x * 16 * 4096;
  int lo0 = w * 512 + lane * 8;  // u16 offset of this lane's 16B chunk
  int lo1 = 2048 + lo0;

  auto stage = [&](int buf, int t) {
    size_t oA = tbA + (size_t)t * 4096;
    size_t oB = tbB + (size_t)t * 4096;
    gl2lds16(AhT + oA + lo0, &lds[buf][0][lo0]);
    gl2lds16(AhT + oA + lo1, &lds[buf][0][lo1]);
    gl2lds16(AlT + oA + lo0, &lds[buf][1][lo0]);
    gl2lds16(AlT + oA + lo1, &lds[buf][1][lo1]);
    gl2lds16(BhT + oB + lo0, &lds[buf][2][lo0]);
    gl2lds16(BhT + oB + lo1, &lds[buf][2][lo1]);
    gl2lds16(BlT + oB + lo0, &lds[buf][3][lo0]);
    gl2lds16(BlT + oB + lo1, &lds[buf][3][lo1]);
  };

  // fragment byte offsets (same XOR as the pre-swizzled tiles)
  unsigned aoff = ((unsigned)((wr * 64 + fr) * 64 + fs * 16)) ^ (((unsigned)(fr & 7)) << 4);
  unsigned boff = ((unsigned)((wc * 64 + fr) * 64 + fs * 16)) ^ (((unsigned)(fr & 7)) << 4);

  f32x4 acc[4][4] = {};

  stage(0, 0);
  __syncthreads();
#pragma unroll 1
  for (int t = 0; t < 16; ++t) {
    int cur = t & 1;
    if (t < 15) stage(cur ^ 1, t + 1);
    bf16x8 ah[4], al[4], bh[4], bl[4];
#pragma unroll
    for (int m = 0; m < 4; ++m) {
      ah[m] = *(const bf16x8*)((const char*)&lds[cur][0][0] + aoff + m * 1024);
      al[m] = *(const bf16x8*)((const char*)&lds[cur][1][0] + aoff + m * 1024);
    }
#pragma unroll
    for (int n = 0; n < 4; ++n) {
      bh[n] = *(const bf16x8*)((const char*)&lds[cur][2][0] + boff + n * 1024);
      bl[n] = *(const bf16x8*)((const char*)&lds[cur][3][0] + boff + n * 1024);
    }
#pragma unroll
    for (int m = 0; m < 4; ++m)
#pragma unroll
      for (int n = 0; n < 4; ++n) {
        acc[m][n] = MFMA16(ah[m], bh[n], acc[m][n]);
        acc[m][n] = MFMA16(ah[m], bl[n], acc[m][n]);
        acc[m][n] = MFMA16(al[m], bh[n], acc[m][n]);
      }
    __syncthreads();
  }
  // epilogue: D frag -> PF.  row = base + fs*4 + r, col = base + fr
  int r0 = blockIdx.y * 128 + wr * 64 + fs * 4;
  int c0 = blockIdx.x * 128 + wc * 64 + fr;
#pragma unroll
  for (int m = 0; m < 4; ++m)
#pragma unroll
    for (int n = 0; n < 4; ++n)
#pragma unroll
      for (int r = 0; r < 4; ++r)
        Cout[(size_t)(r0 + m * 16 + r) * 1024 + (c0 + n * 16)] = acc[m][n][r];
}

// ======================================================================
// Layer GEMM v3 (R9 proven): 64x64 tile, 4x4 micro, VALU-balanced.
// ======================================================================
__global__ __launch_bounds__(256, 4) void k_gemm64(const float* __restrict__ A, int lda, int K,
                                                   const float* __restrict__ W, int mode, int O,
                                                   int twoC, float* __restrict__ Cout, int ldc) {
  __shared__ float As[2][8][64];
  __shared__ float Bs[2][8][64];
  int tid = threadIdx.x;
  int i0 = blockIdx.y * 64, j0 = blockIdx.x * 64;
  int tx = tid & 15, ty = tid >> 4;
  int lr = tid >> 2;          // 0..63: A row / W output-col
  int lc = (tid & 3) * 2;     // k pair 0,2,4,6
  const float* ArowA = A + (size_t)(i0 + lr) * lda;
  int j = j0 + lr;
  float acc[4][4] = {};

  auto stage = [&](int buf, int k0) {
    if ((lda & 1) == 0 && k0 + lc + 2 <= K) {
      float2 av = *(const float2*)(ArowA + k0 + lc);
      As[buf][lc + 0][lr] = av.x;
      As[buf][lc + 1][lr] = av.y;
    } else {
#pragma unroll
      for (int u = 0; u < 2; ++u) {
        int k = k0 + lc + u;
        As[buf][lc + u][lr] = (k < K) ? ArowA[k] : 0.f;
      }
    }
#pragma unroll
    for (int u = 0; u < 2; ++u) {
      int k = k0 + lc + u;
      float wv = 0.f;
      if (k < K) {
        if (mode == 0) wv = W[(size_t)j * K + k];
        else if (j < O) wv = W[(size_t)j * twoC + k];
        else { const float* wr = W + (size_t)(j - O) * twoC; wv = wr[K + k] - wr[k]; }
      }
      Bs[buf][lc + u][lr] = wv;
    }
  };

  stage(0, 0);
  __syncthreads();
  for (int k0 = 0; k0 < K; k0 += 8) {
    int cur = (k0 >> 3) & 1;
    if (k0 + 8 < K) stage(cur ^ 1, k0 + 8);
#pragma unroll
    for (int k = 0; k < 8; ++k) {
      float4 a0 = *(const float4*)&As[cur][k][ty * 4];
      float4 b0 = *(const float4*)&Bs[cur][k][tx * 4];
      float ar[4] = {a0.x, a0.y, a0.z, a0.w};
      float br[4] = {b0.x, b0.y, b0.z, b0.w};
#pragma unroll
      for (int ii = 0; ii < 4; ++ii)
#pragma unroll
        for (int jj = 0; jj < 4; ++jj)
          acc[ii][jj] = fmaf(ar[ii], br[jj], acc[ii][jj]);
    }
    __syncthreads();
  }
#pragma unroll
  for (int ii = 0; ii < 4; ++ii) {
    int row = i0 + ty * 4 + ii;
    float* cr = Cout + (size_t)row * ldc + j0;
    float4 vv = {acc[ii][0], acc[ii][1], acc[ii][2], acc[ii][3]};
    *(float4*)(cr + tx * 4) = vv;
  }
}

// ======================================================================
// Top-20 selection v6 (R10 proven): DS-free reduce + coalesced re-slotted
// candidate mapping m = t4*256 + lane*4 + e.
// ======================================================================

__device__ __forceinline__ unsigned ordf(float f) {
  int u = __float_as_int(f);
  return (unsigned)(u ^ ((u >> 31) | 0x80000000));
}

__device__ __forceinline__ unsigned rowmax16(unsigned v) {
  unsigned t;
  t = (unsigned)__builtin_amdgcn_update_dpp(0, (int)v, 0xB1, 0xF, 0xF, true);   // quad_perm xor1
  v = v > t ? v : t;
  t = (unsigned)__builtin_amdgcn_update_dpp(0, (int)v, 0x4E, 0xF, 0xF, true);   // quad_perm xor2
  v = v > t ? v : t;
  t = (unsigned)__builtin_amdgcn_update_dpp(0, (int)v, 0x141, 0xF, 0xF, true);  // row_half_mirror
  v = v > t ? v : t;
  t = (unsigned)__builtin_amdgcn_update_dpp(0, (int)v, 0x140, 0xF, 0xF, true);  // row_mirror
  v = v > t ? v : t;
  return v;  // all lanes of each 16-lane row hold the row max
}

__device__ __forceinline__ unsigned rowmin16(unsigned v) {
  unsigned t;
  t = (unsigned)__builtin_amdgcn_update_dpp(0, (int)v, 0xB1, 0xF, 0xF, true);
  v = v < t ? v : t;
  t = (unsigned)__builtin_amdgcn_update_dpp(0, (int)v, 0x4E, 0xF, 0xF, true);
  v = v < t ? v : t;
  t = (unsigned)__builtin_amdgcn_update_dpp(0, (int)v, 0x141, 0xF, 0xF, true);
  v = v < t ? v : t;
  t = (unsigned)__builtin_amdgcn_update_dpp(0, (int)v, 0x140, 0xF, 0xF, true);
  v = v < t ? v : t;
  return v;
}

__device__ __forceinline__ unsigned wave_max_u32(unsigned v) {
  v = rowmax16(v);
  unsigned r0 = (unsigned)__builtin_amdgcn_readlane((int)v, 0);
  unsigned r1 = (unsigned)__builtin_amdgcn_readlane((int)v, 16);
  unsigned r2 = (unsigned)__builtin_amdgcn_readlane((int)v, 32);
  unsigned r3 = (unsigned)__builtin_amdgcn_readlane((int)v, 48);
  unsigned a = r0 > r1 ? r0 : r1;
  unsigned b = r2 > r3 ? r2 : r3;
  return a > b ? a : b;  // uniform
}

__device__ __forceinline__ unsigned wave_min_u32(unsigned v) {
  v = rowmin16(v);
  unsigned r0 = (unsigned)__builtin_amdgcn_readlane((int)v, 0);
  unsigned r1 = (unsigned)__builtin_amdgcn_readlane((int)v, 16);
  unsigned r2 = (unsigned)__builtin_amdgcn_readlane((int)v, 32);
  unsigned r3 = (unsigned)__builtin_amdgcn_readlane((int)v, 48);
  unsigned a = r0 < r1 ? r0 : r1;
  unsigned b = r2 < r3 ? r2 : r3;
  return a < b ? a : b;  // uniform
}

// klo for slot t of a lane:  base - ((t>>2)*256 + (t&3)),  base = ~(lane*4)
__device__ __forceinline__ void topk_sel_c(const unsigned* __restrict__ vh, int lane,
                                           int* __restrict__ idxb) {
  unsigned base = ~(unsigned)(lane * 4);
  u64 k1 = 0, k2 = 0;
#pragma unroll
  for (int t = 0; t < 32; ++t) {
    u64 key = ((u64)vh[t] << 32) | (unsigned)(base - ((t >> 2) * 256 + (t & 3)));
    if (key > k1) { k2 = k1; k1 = key; }
    else if (key > k2) { k2 = key; }
  }
  unsigned rm = 0;  // removal bitmask over local slots t
  for (int r = 0; r < KNB; ++r) {
    unsigned o1 = (unsigned)(k1 >> 32);
    unsigned g = wave_max_u32(o1);
    bool matched = (o1 == g);
    u64 bal = __ballot(matched);
    unsigned m1 = ~(unsigned)k1;
    unsigned m_win;
    if (__popcll(bal) == 1) {
      int src = (int)(__ffsll((long long)bal) - 1);
      m_win = (unsigned)__builtin_amdgcn_readlane((int)m1, src);
    } else {
      // exact value tie across lanes: min index wins (rare)
      m_win = wave_min_u32(matched ? m1 : 0xFFFFFFFFu);
    }
    if (lane == 0) idxb[r] = (int)m_win;
    bool mine = matched && (m1 == m_win);
    if (mine) {
      rm |= 1u << (((m_win >> 8) << 2) | (m_win & 3));  // local slot of consumed key
      k1 = k2;
      k2 = 0;
    }
    if (__any(mine && k1 == 0)) {
      if (mine && k1 == 0) {
        u64 a = 0, c = 0;
#pragma unroll
        for (int t = 0; t < 32; ++t) {
          unsigned q = ((rm >> t) & 1u) ? 0u : vh[t];
          u64 key = ((u64)q << 32) | (unsigned)(base - ((t >> 2) * 256 + (t & 3)));
          if (key > a) { c = a; a = key; }
          else if (key > c) { c = key; }
        }
        k1 = a; k2 = c;
      }
    }
  }
}

// ---------------- top-20 (layers 2-4): Gram-based distances
__global__ __launch_bounds__(256) void k_topk(const float* __restrict__ G4,
                                              const float* __restrict__ xx,
                                              int* __restrict__ idx) {
  int tid = threadIdx.x, w = tid >> 6, lane = tid & 63;
  int b = blockIdx.y;
  int n = blockIdx.x * 4 + w;
  const float* Gr = G4 + (size_t)b * NPTS * NPTS + (size_t)n * NPTS;
  const float* xxb = xx + b * NPTS;
  int* idxb = idx + ((size_t)b * NPTS + n) * KNB;
  float xn = xxb[n];
  int mb = lane * 4;
  unsigned vh[32];
#pragma unroll
  for (int t4 = 0; t4 < 8; ++t4) {
    int m0 = t4 * 256 + mb;
    float4 gv = *(const float4*)(Gr + m0);
    float4 xv = *(const float4*)(xxb + m0);
    vh[t4 * 4 + 0] = ordf(2.f * gv.x - xn - xv.x);
    vh[t4 * 4 + 1] = ordf(2.f * gv.y - xn - xv.y);
    vh[t4 * 4 + 2] = ordf(2.f * gv.z - xn - xv.z);
    vh[t4 * 4 + 3] = ordf(2.f * gv.w - xn - xv.w);
  }
  topk_sel_c(vh, lane, idxb);
}

// ---------------- top-20 for layer 1 (K=3): direct distance
__global__ __launch_bounds__(256) void k_topk3(const float* __restrict__ P0,
                                               const float* __restrict__ xx,
                                               int* __restrict__ idx) {
  int tid = threadIdx.x, w = tid >> 6, lane = tid & 63;
  int b = blockIdx.y;
  int n = blockIdx.x * 4 + w;
  const float* Pb = P0 + (size_t)b * NPTS * 3;
  const float* xxb = xx + b * NPTS;
  int* idxb = idx + ((size_t)b * NPTS + n) * KNB;
  float xn0 = Pb[n * 3 + 0], xn1 = Pb[n * 3 + 1], xn2 = Pb[n * 3 + 2];
  float xn = xxb[n];
  int mb = lane * 4;
  unsigned vh[32];
#pragma unroll
  for (int t4 = 0; t4 < 8; ++t4) {
    int m0 = t4 * 256 + mb;
    const float* pm = Pb + (size_t)m0 * 3;
    float4 f0 = *(const float4*)(pm + 0);   // p0.xyz p1.x
    float4 f1 = *(const float4*)(pm + 4);   // p1.yz  p2.xy
    float4 f2 = *(const float4*)(pm + 8);   // p2.z   p3.xyz
    float4 xv = *(const float4*)(xxb + m0);
    float d0 = fmaf(xn2, f0.z, fmaf(xn1, f0.y, fmaf(xn0, f0.x, 0.f)));
    float d1 = fmaf(xn2, f1.y, fmaf(xn1, f1.x, fmaf(xn0, f0.w, 0.f)));
    float d2 = fmaf(xn2, f2.x, fmaf(xn1, f1.w, fmaf(xn0, f1.z, 0.f)));
    float d3 = fmaf(xn2, f2.w, fmaf(xn1, f2.z, fmaf(xn0, f2.y, 0.f)));
    vh[t4 * 4 + 0] = ordf(2.f * d0 - xn - xv.x);
    vh[t4 * 4 + 1] = ordf(2.f * d1 - xn - xv.y);
    vh[t4 * 4 + 2] = ordf(2.f * d2 - xn - xv.z);
    vh[t4 * 4 + 3] = ordf(2.f * d3 - xn - xv.w);
  }
  topk_sel_c(vh, lane, idxb);
}

// ======================================================================
// gather neighbors v2 (R11):
//  (a) all 20 neighbor indices prefetched as 5x int4 -> the 20 Y-row load
//      streams are address-independent (old code serialized ip[k] load ->
//      Yrow load per iteration; VALUBusy was 20% = latency-chain-bound).
//  (b) Pbuf/Qbuf written BLOCK-MAJOR (Pbuf[bid*O + o], contiguous 2KB/blk)
//      instead of channel-major 16KB-stride (one 8B touch per line ->
//      ~30MB/dispatch of partial-line RMW traffic; same mechanism as R7's
//      gram blowup).  k_redstats reads the same values in the same order.
//  Per-channel accumulation order unchanged -> everything bit-identical.
// ======================================================================
__global__ void k_gather(const float* __restrict__ YS, int twoO, int O,
                         const int* __restrict__ idx,
                         float* __restrict__ hmax, float* __restrict__ hmin,
                         double* __restrict__ Pbuf, double* __restrict__ Qbuf) {
  __shared__ float ps[4][256];
  __shared__ float pq[4][256];
  int tid = threadIdx.x, w = tid >> 6, lane = tid & 63;
  int i = blockIdx.x * 4 + w;
  int b = i / NPTS;
  int Q = O >> 6;  // 1,1,2,4
  float s[4], hx[4], hn[4], sm[4], sq[4];
  const float* Srow = YS + (size_t)i * twoO + O;
#pragma unroll
  for (int q = 0; q < 4; ++q) {
    if (q < Q) s[q] = Srow[lane + 64 * q];
    hx[q] = -__builtin_inff(); hn[q] = __builtin_inff(); sm[q] = 0.f; sq[q] = 0.f;
  }
  const int* ip = idx + (size_t)i * KNB;  // 80B, 16B-aligned (20*4*i % 16 == 0)
  int4 iv0 = *(const int4*)(ip + 0);
  int4 iv1 = *(const int4*)(ip + 4);
  int4 iv2 = *(const int4*)(ip + 8);
  int4 iv3 = *(const int4*)(ip + 12);
  int4 iv4 = *(const int4*)(ip + 16);
  int mm[20] = {iv0.x, iv0.y, iv0.z, iv0.w, iv1.x, iv1.y, iv1.z, iv1.w,
                iv2.x, iv2.y, iv2.z, iv2.w, iv3.x, iv3.y, iv3.z, iv3.w,
                iv4.x, iv4.y, iv4.z, iv4.w};
#pragma unroll
  for (int k = 0; k < KNB; ++k) {
    int m = mm[k];
    const float* Yrow = YS + (size_t)(b * NPTS + m) * twoO;
#pragma unroll
    for (int q = 0; q < 4; ++q) {
      if (q < Q) {
        float h = Yrow[lane + 64 * q] + s[q];
        hx[q] = fmaxf(hx[q], h);
        hn[q] = fminf(hn[q], h);
        sm[q] += h;
        sq[q] = fmaf(h, h, sq[q]);
      }
    }
  }
#pragma unroll
  for (int q = 0; q < 4; ++q) {
    if (q < Q) {
      int o = lane + 64 * q;
      hmax[(size_t)i * O + o] = hx[q];
      hmin[(size_t)i * O + o] = hn[q];
      ps[w][o] = sm[q];
      pq[w][o] = sq[q];
    }
  }
  __syncthreads();
  if (tid < O) {
    double t1 = (double)(ps[0][tid] + ps[1][tid] + ps[2][tid] + ps[3][tid]);
    double t2 = (double)(pq[0][tid] + pq[1][tid] + pq[2][tid] + pq[3][tid]);
    Pbuf[(size_t)blockIdx.x * O + tid] = t1;   // block-major: contiguous 2KB/blk
    Qbuf[(size_t)blockIdx.x * O + tid] = t2;
  }
}

// ---------------- deterministic reduce of 2048 partials per channel.
// R11: Pbuf is block-major (Pbuf[blk*O + o], O = gridDim.x).  Same values
// summed in the same order as before -> scale/shift bit-identical.
__global__ __launch_bounds__(256) void k_redstats(const double* __restrict__ Pbuf,
                                                  const double* __restrict__ Qbuf,
                                                  const float* __restrict__ g,
                                                  const float* __restrict__ bb, float cnt,
                                                  float* __restrict__ scale,
                                                  float* __restrict__ shift) {
  __shared__ double s1[256], s2[256];
  int o = blockIdx.x, t = threadIdx.x;
  int O = gridDim.x;
  double a = 0.0, c = 0.0;
#pragma unroll
  for (int j = 0; j < 8; ++j) {
    a += Pbuf[(size_t)(t + 256 * j) * O + o];
    c += Qbuf[(size_t)(t + 256 * j) * O + o];
  }
  s1[t] = a; s2[t] = c;
  __syncthreads();
  for (int s = 128; s; s >>= 1) {
    if (t < s) { s1[t] += s1[t + s]; s2[t] += s2[t + s]; }
    __syncthreads();
  }
  if (t == 0) {
    double mean = s1[0] / (double)cnt;
    double var = s2[0] / (double)cnt - mean * mean;
    double sc = (double)g[o] / sqrt(var + 1e-5);
    scale[o] = (float)sc;
    shift[o] = (float)((double)bb[o] - mean * sc);
  }
}

// ---------------- apply BN+lrelu (frozen)
__global__ void k_apply(const float* __restrict__ hmax, const float* __restrict__ hmin,
                        const float* __restrict__ scale, const float* __restrict__ shift,
                        float* __restrict__ Fout, int O) {
  int t = blockIdx.x * 256 + threadIdx.x;
  int i = t / O, o = t % O;
  float sc = scale[o];
  float h = (sc >= 0.f) ? hmax[t] : hmin[t];
  float v = fmaf(sc, h, shift[o]);
  Fout[(size_t)i * 512 + o] = (v >= 0.f) ? v : 0.2f * v;
}

// ---------------- final BN partials (R10: column-split grid (64,4))
__global__ void k_fstats(const float* __restrict__ PF, double* __restrict__ Fb,
                         double* __restrict__ Qb) {
  int tid = threadIdx.x, bid = blockIdx.x;
  int o = blockIdx.y * 256 + tid;
  float sm = 0.f, sq = 0.f;
  int r0 = bid * 128;
  for (int r = 0; r < 128; ++r) {
    float v = PF[(size_t)(r0 + r) * 1024 + o];
    sm += v;
    sq = fmaf(v, v, sq);
  }
  Fb[(size_t)o * 64 + bid] = (double)sm;
  Qb[(size_t)o * 64 + bid] = (double)sq;
}

// ---------------- deterministic reduce -> sc5/sh5 (frozen)
__global__ __launch_bounds__(64) void k_red5(const double* __restrict__ Fb,
                                             const double* __restrict__ Qb,
                                             const float* __restrict__ g,
                                             const float* __restrict__ bb,
                                             float* __restrict__ sc5, float* __restrict__ sh5) {
  __shared__ double s1[64], s2[64];
  int o = blockIdx.x, t = threadIdx.x;
  s1[t] = Fb[(size_t)o * 64 + t];
  s2[t] = Qb[(size_t)o * 64 + t];
  __syncthreads();
  for (int s = 32; s; s >>= 1) {
    if (t < s) { s1[t] += s1[t + s]; s2[t] += s2[t + s]; }
    __syncthreads();
  }
  if (t == 0) {
    double cnt = (double)TOTP;
    double mean = s1[0] / cnt;
    double var = s2[0] / cnt - mean * mean;
    double sc = (double)g[o] / sqrt(var + 1e-5);
    sc5[o] = (float)sc;
    sh5[o] = (float)((double)bb[o] - mean * sc);
  }
}

// ---------------- out0 (frozen)
__global__ void k_out0(const float* __restrict__ PF, const float* __restrict__ sc5,
                       const float* __restrict__ sh5, float* __restrict__ out0) {
  __shared__ float t[64][65];
  int b = blockIdx.z, p0 = blockIdx.y * 64, o0 = blockIdx.x * 64;
  int ol = threadIdx.x & 63, pg = threadIdx.x >> 6;
#pragma unroll
  for (int q = 0; q < 16; ++q) {
    int p = q * 4 + pg;
    t[p][ol] = PF[((size_t)(b * NPTS + p0 + p)) * 1024 + o0 + ol];
  }
  __syncthreads();
#pragma unroll
  for (int q = 0; q < 16; ++q) {
    int oo = q * 4 + pg;
    int o = o0 + oo;
    float v = fmaf(sc5[o], t[ol][oo], sh5[o]);
    float a = (v >= 0.f) ? v : 0.2f * v;
    out0[((size_t)(b * 1024 + o)) * 128 + p0 + ol] = a;
  }
}

// ---------------- per-(b,nb,o) max (frozen)
__global__ void k_gmax(const float* __restrict__ PF, const float* __restrict__ sc5,
                       const float* __restrict__ sh5, float* __restrict__ tmpmax) {
  int b = blockIdx.z, nb = blockIdx.y;
  int o = blockIdx.x * 256 + threadIdx.x;
  const float* base = PF + ((size_t)(b * NPTS + nb * 128)) * 1024 + o;
  float sc = sc5[o], sh = sh5[o];
  float m0 = -__builtin_inff(), m1 = m0, m2 = m0, m3 = m0;
  for (int p = 0; p < 128; p += 4) {
    float v0 = base[(size_t)(p + 0) * 1024];
    float v1 = base[(size_t)(p + 1) * 1024];
    float v2 = base[(size_t)(p + 2) * 1024];
    float v3 = base[(size_t)(p + 3) * 1024];
    float a0 = fmaf(sc, v0, sh); a0 = (a0 >= 0.f) ? a0 : 0.2f * a0;
    float a1 = fmaf(sc, v1, sh); a1 = (a1 >= 0.f) ? a1 : 0.2f * a1;
    float a2 = fmaf(sc, v2, sh); a2 = (a2 >= 0.f) ? a2 : 0.2f * a2;
    float a3 = fmaf(sc, v3, sh); a3 = (a3 >= 0.f) ? a3 : 0.2f * a3;
    m0 = fmaxf(m0, a0); m1 = fmaxf(m1, a1);
    m2 = fmaxf(m2, a2); m3 = fmaxf(m3, a3);
  }
  tmpmax[(size_t)(b * 16 + nb) * 1024 + o] = fmaxf(fmaxf(m0, m1), fmaxf(m2, m3));
}

// ---------------- gout duplication (frozen)
__global__ void k_gdup(const float* __restrict__ tmpmax, float* __restrict__ gout) {
  __shared__ float t[16][65];
  int b = blockIdx.y, o0 = blockIdx.x * 64;
  int ol = threadIdx.x & 63, ng = threadIdx.x >> 6;
#pragma unroll
  for (int q = 0; q < 4; ++q) {
    int nb = q * 4 + ng;
    t[nb][ol] = tmpmax[(size_t)(b * 16 + nb) * 1024 + o0 + ol];
  }
  __syncthreads();
  int nb2 = threadIdx.x & 15, og = threadIdx.x >> 4;
#pragma unroll
  for (int q = 0; q < 4; ++q) {
    int oo = q * 16 + og;
    float v = t[nb2][oo];
    size_t base = ((size_t)(b * 2048) + o0 + oo) * 16 + nb2;
    gout[base] = v;
    gout[base + 1024 * 16] = v;
  }
}

extern "C" void kernel_launch(void* const* d_in, const int* in_sizes, int n_in,
                              void* d_out, int out_size, void* d_ws, size_t ws_size,
                              hipStream_t stream) {
  const float* x  = (const float*)d_in[0];
  const float* W1 = (const float*)d_in[1];
  const float* W2 = (const float*)d_in[2];
  const float* W3 = (const float*)d_in[3];
  const float* W4 = (const float*)d_in[4];
  const float* W5 = (const float*)d_in[5];
  const float* g1 = (const float*)d_in[6];  const float* b1 = (const float*)d_in[7];
  const float* g2 = (const float*)d_in[8];  const float* b2 = (const float*)d_in[9];
  const float* g3 = (const float*)d_in[10]; const float* b3 = (const float*)d_in[11];
  const float* g4 = (const float*)d_in[12]; const float* b4 = (const float*)d_in[13];
  const float* g5 = (const float*)d_in[14]; const float* b5 = (const float*)d_in[15];

  float* ws = (float*)d_ws;
  size_t off = 0;
  auto alloc = [&](size_t nfl) { float* p = ws + off; off += (nfl + 63) & ~(size_t)63; return p; };
  float*  P0   = alloc((size_t)TOTP * 3);
  float*  F    = alloc((size_t)TOTP * 512);
  float*  xx   = alloc(TOTP);
  // Union U (16.78M floats): G4 lives during gram+topk of layers 2-4;
  // YS/hmax/hmin live during gemm..apply; PF lives after the last topk.
  // During the final GEMM, U[0 .. 8.39M floats) (ex-YS/hmax/hmin) is dead
  // and is reused for the pre-swizzled split-bf16 tiles (18.9 MB < 33.5 MB).
  float*  U    = alloc((size_t)BN_ * NPTS * NPTS);
  float*  G4   = U;
  float*  YS   = U;
  float*  hmax = U + (size_t)TOTP * 512;
  float*  hmin = hmax + (size_t)TOTP * 256;
  float*  PF   = hmin + (size_t)TOTP * 256;
  float*  tmpmax = alloc((size_t)BN_ * 16 * 1024);
  double* Pbuf = (double*)alloc((size_t)256 * 2048 * 2);
  double* Qbuf = (double*)alloc((size_t)256 * 2048 * 2);
  double* Fb   = (double*)alloc((size_t)1024 * 64 * 2);
  double* Qb   = (double*)alloc((size_t)1024 * 64 * 2);
  float*  scale= alloc(256);
  float*  shift= alloc(256);
  float*  sc5  = alloc(1024);
  float*  sh5  = alloc(1024);
  int*    idx  = (int*)alloc((size_t)TOTP * KNB);

  k_transpose<<<32, 256, 0, stream>>>(x, P0);

  struct L { const float* base; int lda, C, O, colout; const float* W; const float* g; const float* b; };
  L Ls[4] = {
    {P0,      3,   3,   64,  0,   W1, g1, b1},
    {F,       512, 64,  64,  64,  W2, g2, b2},
    {F + 64,  512, 64,  128, 128, W3, g3, b3},
    {F + 128, 512, 128, 256, 256, W4, g4, b4},
  };

  for (int l = 0; l < 4; ++l) {
    const L& a = Ls[l];
    k_sqnorm<<<32, 256, 0, stream>>>(a.base, a.lda, a.C, xx);
    if (l == 0) {
      k_topk3<<<dim3(512, BN_), 256, 0, stream>>>(P0, xx, idx);
    } else {
      k_gram64<<<dim3(528, 1, BN_), 256, 0, stream>>>(a.base, a.lda, a.C, G4);
      k_topk<<<dim3(512, BN_), 256, 0, stream>>>(G4, xx, idx);
    }
    int twoO = 2 * a.O;
    k_gemm64<<<dim3(twoO / 64, TOTP / 64), 256, 0, stream>>>(
        a.base, a.lda, a.C, a.W, 1, a.O, 2 * a.C, YS, twoO);
    k_gather<<<TOTP / 4, 256, 0, stream>>>(YS, twoO, a.O, idx, hmax, hmin, Pbuf, Qbuf);
    k_redstats<<<a.O, 256, 0, stream>>>(Pbuf, Qbuf, a.g, a.b, (float)(BN_ * NPTS * KNB),
                                        scale, shift);
    k_apply<<<TOTP * a.O / 256, 256, 0, stream>>>(hmax, hmin, scale, shift, F + a.colout, a.O);
  }

  // final: PF = F(8192x512) * W5^T(512x1024) via split-bf16 3-pass MFMA
  // pre-swizzled hi/lo tiles live in the dead YS/hmax/hmin region of U
  u16* FhT = (u16*)U;                       // 8192x512 -> 1024 tiles * 8KB
  u16* FlT = FhT + (size_t)4194304;
  u16* WhT = FlT + (size_t)4194304;         // 1024x512 -> 128 tiles * 8KB
  u16* WlT = WhT + (size_t)524288;
  k_split_swz<<<2048, 256, 0, stream>>>(F, FhT, FlT);
  k_split_swz<<<256, 256, 0, stream>>>(W5, WhT, WlT);
  k_gemm_mfma<<<dim3(8, 64), 256, 0, stream>>>(FhT, FlT, WhT, WlT, PF);

  k_fstats<<<dim3(64, 4), 256, 0, stream>>>(PF, Fb, Qb);
  k_red5<<<1024, 64, 0, stream>>>(Fb, Qb, g5, b5, sc5, sh5);

  float* out0 = (float*)d_out;
  float* gout = out0 + (size_t)BN_ * 1024 * 128;
  k_out0<<<dim3(16, 2, BN_), 256, 0, stream>>>(PF, sc5, sh5, out0);
  k_gmax<<<dim3(4, 16, BN_), 256, 0, stream>>>(PF, sc5, sh5, tmpmax);
  k_gdup<<<dim3(16, BN_), 256, 0, stream>>>(tmpmax, gout);
}

// Round 12
// 601.007 us; speedup vs baseline: 1.0521x; 1.0521x over previous
//
#include <hip/hip_runtime.h>
#include <cstdint>
#include <cmath>

#define BN_ 4
#define NPTS 2048
#define KNB 20
#define TOTP (BN_ * NPTS)   // 8192

typedef unsigned short u16;
typedef unsigned long long u64;
typedef short bf16x8 __attribute__((ext_vector_type(8)));
typedef u16 u16x8 __attribute__((ext_vector_type(8)));
typedef float f32x4 __attribute__((ext_vector_type(4)));

// ---------------- transpose x (B,3,N) -> P0 (B*N, 3)
__global__ void k_transpose(const float* __restrict__ x, float* __restrict__ P0) {
  int i = blockIdx.x * 256 + threadIdx.x;
  if (i >= TOTP) return;
  int b = i / NPTS, n = i % NPTS;
#pragma unroll
  for (int c = 0; c < 3; ++c)
    P0[i * 3 + c] = x[((size_t)b * 3 + c) * NPTS + n];
}

// ---------------- squared norms per point
__global__ void k_sqnorm(const float* __restrict__ base, int ld, int C, float* __restrict__ xx) {
  int i = blockIdx.x * 256 + threadIdx.x;
  if (i >= TOTP) return;
  const float* r = base + (size_t)i * ld;
  float s = 0.f;
  for (int c = 0; c < C; ++c) s = fmaf(r[c], r[c], s);
  xx[i] = s;
}

// ======================================================================
// Symmetric Gram: 64x64 tiles, __launch_bounds__(256,4).  (R10 proven:
// LDS-transposed mirror write -> contiguous 256B rows.)
// ======================================================================
__global__ __launch_bounds__(256, 4) void k_gram64(const float* __restrict__ A_all, int lda,
                                                   int K, float* __restrict__ G4) {
  __shared__ float As[2][8][64];
  __shared__ float Bs[2][8][64];
  __shared__ float tb[64][68];  // [col_local][row_local], row stride 272B (16B-aligned)
  const int T = NPTS / 64;  // 32
  int q = blockIdx.x;
  int bi = 0;
  while (q >= T - bi) { q -= T - bi; ++bi; }
  int bj = bi + q;
  int b = blockIdx.z;
  const float* A = A_all + (size_t)b * NPTS * lda;
  float* G = G4 + (size_t)b * NPTS * NPTS;
  int tid = threadIdx.x;
  int i0 = bi * 64, m0 = bj * 64;
  int tx = tid & 15, ty = tid >> 4;
  int lr = tid >> 2;          // 0..63
  int lc = (tid & 3) * 2;     // 0,2,4,6
  const float* Arow = A + (size_t)(i0 + lr) * lda;
  const float* Brow = A + (size_t)(m0 + lr) * lda;
  float acc[4][4] = {};
  float2 pa, pb;

  pa = *(const float2*)(Arow + lc);
  pb = *(const float2*)(Brow + lc);
  As[0][lc + 0][lr] = pa.x; As[0][lc + 1][lr] = pa.y;
  Bs[0][lc + 0][lr] = pb.x; Bs[0][lc + 1][lr] = pb.y;
  __syncthreads();
  for (int k0 = 0; k0 < K; k0 += 8) {
    int cur = (k0 >> 3) & 1;
    bool more = (k0 + 8 < K);
    if (more) {
      pa = *(const float2*)(Arow + k0 + 8 + lc);
      pb = *(const float2*)(Brow + k0 + 8 + lc);
    }
#pragma unroll
    for (int k = 0; k < 8; ++k) {
      float4 a0 = *(const float4*)&As[cur][k][ty * 4];
      float4 b0 = *(const float4*)&Bs[cur][k][tx * 4];
      float ar[4] = {a0.x, a0.y, a0.z, a0.w};
      float br[4] = {b0.x, b0.y, b0.z, b0.w};
#pragma unroll
      for (int ii = 0; ii < 4; ++ii)
#pragma unroll
        for (int jj = 0; jj < 4; ++jj)
          acc[ii][jj] = fmaf(ar[ii], br[jj], acc[ii][jj]);
    }
    if (more) {
      int nxt = cur ^ 1;
      As[nxt][lc + 0][lr] = pa.x; As[nxt][lc + 1][lr] = pa.y;
      Bs[nxt][lc + 0][lr] = pb.x; Bs[nxt][lc + 1][lr] = pb.y;
    }
    __syncthreads();
  }
#pragma unroll
  for (int ii = 0; ii < 4; ++ii) {
    int row = i0 + ty * 4 + ii;
    float4 vv = {acc[ii][0], acc[ii][1], acc[ii][2], acc[ii][3]};
    *(float4*)(G + (size_t)row * NPTS + m0 + tx * 4) = vv;
  }
  if (bi != bj) {
    // stage transposed: tb[col_local][row_local] = acc[row_l][col_l]
#pragma unroll
    for (int jj = 0; jj < 4; ++jj) {
      float4 vv = {acc[0][jj], acc[1][jj], acc[2][jj], acc[3][jj]};
      *(float4*)&tb[tx * 4 + jj][ty * 4] = vv;
    }
    __syncthreads();
    int cl0 = tid >> 4;        // 0..15
    int cc = (tid & 15) * 4;   // 0..60
#pragma unroll
    for (int qq = 0; qq < 4; ++qq) {
      int cl = qq * 16 + cl0;
      float4 vv = *(const float4*)&tb[cl][cc];
      *(float4*)(G + (size_t)(m0 + cl) * NPTS + i0 + cc) = vv;  // 256B-contig rows
    }
  }
}

// ======================================================================
// Final GEMM via split-bf16 (hi/lo) 3-pass MFMA (R0 proven).
// ======================================================================

__device__ __forceinline__ u16 bf16_rn(float f) {
  unsigned u = __float_as_uint(f);
  unsigned r = u + 0x7fffu + ((u >> 16) & 1u);
  return (u16)(r >> 16);
}

// one thread per 8-element k-chunk; src is row-major [rows][512]
__global__ __launch_bounds__(256) void k_split_swz(const float* __restrict__ src,
                                                   u16* __restrict__ dh,
                                                   u16* __restrict__ dl) {
  int c = blockIdx.x * 256 + threadIdx.x;
  int row = c >> 6;            // 64 chunks per row (512/8)
  int k0 = (c & 63) << 3;      // 0..504
  const float4* s = (const float4*)(src + (size_t)row * 512 + k0);
  float4 v0 = s[0], v1 = s[1];
  float vv[8] = {v0.x, v0.y, v0.z, v0.w, v1.x, v1.y, v1.z, v1.w};
  u16x8 hv, lv;
#pragma unroll
  for (int e = 0; e < 8; ++e) {
    u16 h = bf16_rn(vv[e]);
    float fh = __uint_as_float((unsigned)h << 16);
    hv[e] = h;
    lv[e] = bf16_rn(vv[e] - fh);
  }
  int tr = row >> 7, rloc = row & 127, tk = k0 >> 5, ss = (k0 >> 3) & 3;
  size_t tb = ((size_t)(tr * 16 + tk)) * 4096;  // tile base in u16 units (8KB)
  unsigned P = ((unsigned)(rloc * 64 + ss * 16)) ^ (((unsigned)(rloc & 7)) << 4);
  *(u16x8*)(dh + tb + (P >> 1)) = hv;
  *(u16x8*)(dl + tb + (P >> 1)) = lv;
}

__device__ __forceinline__ void gl2lds16(const void* g, void* l) {
  __builtin_amdgcn_global_load_lds(
      (const __attribute__((address_space(1))) unsigned int*)g,
      (__attribute__((address_space(3))) unsigned int*)l, 16, 0, 0);
}

#define MFMA16(A, B, C) __builtin_amdgcn_mfma_f32_16x16x32_bf16(A, B, C, 0, 0, 0)

__global__ __launch_bounds__(256, 2) void k_gemm_mfma(
    const u16* __restrict__ AhT, const u16* __restrict__ AlT,
    const u16* __restrict__ BhT, const u16* __restrict__ BlT,
    float* __restrict__ Cout) {
  // block: 128x128 tile; 4 waves, each 64x64 (4x4 frags of 16x16); BK=32
  __shared__ u16 lds[2][4][4096];  // [buf][Ah,Al,Bh,Bl][8KB tile]  = 64 KB
  int tid = threadIdx.x;
  int w = tid >> 6, lane = tid & 63;
  int wr = w >> 1, wc = w & 1;
  int fr = lane & 15, fs = lane >> 4;

  size_t tbA = (size_t)blockIdx.y * 16 * 4096;  // u16 units
  size_t tbB = (size_t)blockIdx.x * 16 * 4096;
  int lo0 = w * 512 + lane * 8;  // u16 offset of this lane's 16B chunk
  int lo1 = 2048 + lo0;

  auto stage = [&](int buf, int t) {
    size_t oA = tbA + (size_t)t * 4096;
    size_t oB = tbB + (size_t)t * 4096;
    gl2lds16(AhT + oA + lo0, &lds[buf][0][lo0]);
    gl2lds16(AhT + oA + lo1, &lds[buf][0][lo1]);
    gl2lds16(AlT + oA + lo0, &lds[buf][1][lo0]);
    gl2lds16(AlT + oA + lo1, &lds[buf][1][lo1]);
    gl2lds16(BhT + oB + lo0, &lds[buf][2][lo0]);
    gl2lds16(BhT + oB + lo1, &lds[buf][2][lo1]);
    gl2lds16(BlT + oB + lo0, &lds[buf][3][lo0]);
    gl2lds16(BlT + oB + lo1, &lds[buf][3][lo1]);
  };

  // fragment byte offsets (same XOR as the pre-swizzled tiles)
  unsigned aoff = ((unsigned)((wr * 64 + fr) * 64 + fs * 16)) ^ (((unsigned)(fr & 7)) << 4);
  unsigned boff = ((unsigned)((wc * 64 + fr) * 64 + fs * 16)) ^ (((unsigned)(fr & 7)) << 4);

  f32x4 acc[4][4] = {};

  stage(0, 0);
  __syncthreads();
#pragma unroll 1
  for (int t = 0; t < 16; ++t) {
    int cur = t & 1;
    if (t < 15) stage(cur ^ 1, t + 1);
    bf16x8 ah[4], al[4], bh[4], bl[4];
#pragma unroll
    for (int m = 0; m < 4; ++m) {
      ah[m] = *(const bf16x8*)((const char*)&lds[cur][0][0] + aoff + m * 1024);
      al[m] = *(const bf16x8*)((const char*)&lds[cur][1][0] + aoff + m * 1024);
    }
#pragma unroll
    for (int n = 0; n < 4; ++n) {
      bh[n] = *(const bf16x8*)((const char*)&lds[cur][2][0] + boff + n * 1024);
      bl[n] = *(const bf16x8*)((const char*)&lds[cur][3][0] + boff + n * 1024);
    }
#pragma unroll
    for (int m = 0; m < 4; ++m)
#pragma unroll
      for (int n = 0; n < 4; ++n) {
        acc[m][n] = MFMA16(ah[m], bh[n], acc[m][n]);
        acc[m][n] = MFMA16(ah[m], bl[n], acc[m][n]);
        acc[m][n] = MFMA16(al[m], bh[n], acc[m][n]);
      }
    __syncthreads();
  }
  // epilogue: D frag -> PF.  row = base + fs*4 + r, col = base + fr
  int r0 = blockIdx.y * 128 + wr * 64 + fs * 4;
  int c0 = blockIdx.x * 128 + wc * 64 + fr;
#pragma unroll
  for (int m = 0; m < 4; ++m)
#pragma unroll
    for (int n = 0; n < 4; ++n)
#pragma unroll
      for (int r = 0; r < 4; ++r)
        Cout[(size_t)(r0 + m * 16 + r) * 1024 + (c0 + n * 16)] = acc[m][n][r];
}

// ======================================================================
// Layer GEMM v3 (R9 proven): 64x64 tile, 4x4 micro, VALU-balanced.
// ======================================================================
__global__ __launch_bounds__(256, 4) void k_gemm64(const float* __restrict__ A, int lda, int K,
                                                   const float* __restrict__ W, int mode, int O,
                                                   int twoC, float* __restrict__ Cout, int ldc) {
  __shared__ float As[2][8][64];
  __shared__ float Bs[2][8][64];
  int tid = threadIdx.x;
  int i0 = blockIdx.y * 64, j0 = blockIdx.x * 64;
  int tx = tid & 15, ty = tid >> 4;
  int lr = tid >> 2;          // 0..63: A row / W output-col
  int lc = (tid & 3) * 2;     // k pair 0,2,4,6
  const float* ArowA = A + (size_t)(i0 + lr) * lda;
  int j = j0 + lr;
  float acc[4][4] = {};

  auto stage = [&](int buf, int k0) {
    if ((lda & 1) == 0 && k0 + lc + 2 <= K) {
      float2 av = *(const float2*)(ArowA + k0 + lc);
      As[buf][lc + 0][lr] = av.x;
      As[buf][lc + 1][lr] = av.y;
    } else {
#pragma unroll
      for (int u = 0; u < 2; ++u) {
        int k = k0 + lc + u;
        As[buf][lc + u][lr] = (k < K) ? ArowA[k] : 0.f;
      }
    }
#pragma unroll
    for (int u = 0; u < 2; ++u) {
      int k = k0 + lc + u;
      float wv = 0.f;
      if (k < K) {
        if (mode == 0) wv = W[(size_t)j * K + k];
        else if (j < O) wv = W[(size_t)j * twoC + k];
        else { const float* wr = W + (size_t)(j - O) * twoC; wv = wr[K + k] - wr[k]; }
      }
      Bs[buf][lc + u][lr] = wv;
    }
  };

  stage(0, 0);
  __syncthreads();
  for (int k0 = 0; k0 < K; k0 += 8) {
    int cur = (k0 >> 3) & 1;
    if (k0 + 8 < K) stage(cur ^ 1, k0 + 8);
#pragma unroll
    for (int k = 0; k < 8; ++k) {
      float4 a0 = *(const float4*)&As[cur][k][ty * 4];
      float4 b0 = *(const float4*)&Bs[cur][k][tx * 4];
      float ar[4] = {a0.x, a0.y, a0.z, a0.w};
      float br[4] = {b0.x, b0.y, b0.z, b0.w};
#pragma unroll
      for (int ii = 0; ii < 4; ++ii)
#pragma unroll
        for (int jj = 0; jj < 4; ++jj)
          acc[ii][jj] = fmaf(ar[ii], br[jj], acc[ii][jj]);
    }
    __syncthreads();
  }
#pragma unroll
  for (int ii = 0; ii < 4; ++ii) {
    int row = i0 + ty * 4 + ii;
    float* cr = Cout + (size_t)row * ldc + j0;
    float4 vv = {acc[ii][0], acc[ii][1], acc[ii][2], acc[ii][3]};
    *(float4*)(cr + tx * 4) = vv;
  }
}

// ======================================================================
// Top-20 selection v6 (R10 proven): DS-free reduce + coalesced re-slotted
// candidate mapping m = t4*256 + lane*4 + e.
// ======================================================================

__device__ __forceinline__ unsigned ordf(float f) {
  int u = __float_as_int(f);
  return (unsigned)(u ^ ((u >> 31) | 0x80000000));
}

__device__ __forceinline__ unsigned rowmax16(unsigned v) {
  unsigned t;
  t = (unsigned)__builtin_amdgcn_update_dpp(0, (int)v, 0xB1, 0xF, 0xF, true);   // quad_perm xor1
  v = v > t ? v : t;
  t = (unsigned)__builtin_amdgcn_update_dpp(0, (int)v, 0x4E, 0xF, 0xF, true);   // quad_perm xor2
  v = v > t ? v : t;
  t = (unsigned)__builtin_amdgcn_update_dpp(0, (int)v, 0x141, 0xF, 0xF, true);  // row_half_mirror
  v = v > t ? v : t;
  t = (unsigned)__builtin_amdgcn_update_dpp(0, (int)v, 0x140, 0xF, 0xF, true);  // row_mirror
  v = v > t ? v : t;
  return v;  // all lanes of each 16-lane row hold the row max
}

__device__ __forceinline__ unsigned rowmin16(unsigned v) {
  unsigned t;
  t = (unsigned)__builtin_amdgcn_update_dpp(0, (int)v, 0xB1, 0xF, 0xF, true);
  v = v < t ? v : t;
  t = (unsigned)__builtin_amdgcn_update_dpp(0, (int)v, 0x4E, 0xF, 0xF, true);
  v = v < t ? v : t;
  t = (unsigned)__builtin_amdgcn_update_dpp(0, (int)v, 0x141, 0xF, 0xF, true);
  v = v < t ? v : t;
  t = (unsigned)__builtin_amdgcn_update_dpp(0, (int)v, 0x140, 0xF, 0xF, true);
  v = v < t ? v : t;
  return v;
}

__device__ __forceinline__ unsigned wave_max_u32(unsigned v) {
  v = rowmax16(v);
  unsigned r0 = (unsigned)__builtin_amdgcn_readlane((int)v, 0);
  unsigned r1 = (unsigned)__builtin_amdgcn_readlane((int)v, 16);
  unsigned r2 = (unsigned)__builtin_amdgcn_readlane((int)v, 32);
  unsigned r3 = (unsigned)__builtin_amdgcn_readlane((int)v, 48);
  unsigned a = r0 > r1 ? r0 : r1;
  unsigned b = r2 > r3 ? r2 : r3;
  return a > b ? a : b;  // uniform
}

__device__ __forceinline__ unsigned wave_min_u32(unsigned v) {
  v = rowmin16(v);
  unsigned r0 = (unsigned)__builtin_amdgcn_readlane((int)v, 0);
  unsigned r1 = (unsigned)__builtin_amdgcn_readlane((int)v, 16);
  unsigned r2 = (unsigned)__builtin_amdgcn_readlane((int)v, 32);
  unsigned r3 = (unsigned)__builtin_amdgcn_readlane((int)v, 48);
  unsigned a = r0 < r1 ? r0 : r1;
  unsigned b = r2 < r3 ? r2 : r3;
  return a < b ? a : b;  // uniform
}

// klo for slot t of a lane:  base - ((t>>2)*256 + (t&3)),  base = ~(lane*4)
__device__ __forceinline__ void topk_sel_c(const unsigned* __restrict__ vh, int lane,
                                           int* __restrict__ idxb) {
  unsigned base = ~(unsigned)(lane * 4);
  u64 k1 = 0, k2 = 0;
#pragma unroll
  for (int t = 0; t < 32; ++t) {
    u64 key = ((u64)vh[t] << 32) | (unsigned)(base - ((t >> 2) * 256 + (t & 3)));
    if (key > k1) { k2 = k1; k1 = key; }
    else if (key > k2) { k2 = key; }
  }
  unsigned rm = 0;  // removal bitmask over local slots t
  for (int r = 0; r < KNB; ++r) {
    unsigned o1 = (unsigned)(k1 >> 32);
    unsigned g = wave_max_u32(o1);
    bool matched = (o1 == g);
    u64 bal = __ballot(matched);
    unsigned m1 = ~(unsigned)k1;
    unsigned m_win;
    if (__popcll(bal) == 1) {
      int src = (int)(__ffsll((long long)bal) - 1);
      m_win = (unsigned)__builtin_amdgcn_readlane((int)m1, src);
    } else {
      // exact value tie across lanes: min index wins (rare)
      m_win = wave_min_u32(matched ? m1 : 0xFFFFFFFFu);
    }
    if (lane == 0) idxb[r] = (int)m_win;
    bool mine = matched && (m1 == m_win);
    if (mine) {
      rm |= 1u << (((m_win >> 8) << 2) | (m_win & 3));  // local slot of consumed key
      k1 = k2;
      k2 = 0;
    }
    if (__any(mine && k1 == 0)) {
      if (mine && k1 == 0) {
        u64 a = 0, c = 0;
#pragma unroll
        for (int t = 0; t < 32; ++t) {
          unsigned q = ((rm >> t) & 1u) ? 0u : vh[t];
          u64 key = ((u64)q << 32) | (unsigned)(base - ((t >> 2) * 256 + (t & 3)));
          if (key > a) { c = a; a = key; }
          else if (key > c) { c = key; }
        }
        k1 = a; k2 = c;
      }
    }
  }
}

// ---------------- top-20 (layers 2-4): Gram-based distances
__global__ __launch_bounds__(256) void k_topk(const float* __restrict__ G4,
                                              const float* __restrict__ xx,
                                              int* __restrict__ idx) {
  int tid = threadIdx.x, w = tid >> 6, lane = tid & 63;
  int b = blockIdx.y;
  int n = blockIdx.x * 4 + w;
  const float* Gr = G4 + (size_t)b * NPTS * NPTS + (size_t)n * NPTS;
  const float* xxb = xx + b * NPTS;
  int* idxb = idx + ((size_t)b * NPTS + n) * KNB;
  float xn = xxb[n];
  int mb = lane * 4;
  unsigned vh[32];
#pragma unroll
  for (int t4 = 0; t4 < 8; ++t4) {
    int m0 = t4 * 256 + mb;
    float4 gv = *(const float4*)(Gr + m0);
    float4 xv = *(const float4*)(xxb + m0);
    vh[t4 * 4 + 0] = ordf(2.f * gv.x - xn - xv.x);
    vh[t4 * 4 + 1] = ordf(2.f * gv.y - xn - xv.y);
    vh[t4 * 4 + 2] = ordf(2.f * gv.z - xn - xv.z);
    vh[t4 * 4 + 3] = ordf(2.f * gv.w - xn - xv.w);
  }
  topk_sel_c(vh, lane, idxb);
}

// ---------------- top-20 for layer 1 (K=3): direct distance
__global__ __launch_bounds__(256) void k_topk3(const float* __restrict__ P0,
                                               const float* __restrict__ xx,
                                               int* __restrict__ idx) {
  int tid = threadIdx.x, w = tid >> 6, lane = tid & 63;
  int b = blockIdx.y;
  int n = blockIdx.x * 4 + w;
  const float* Pb = P0 + (size_t)b * NPTS * 3;
  const float* xxb = xx + b * NPTS;
  int* idxb = idx + ((size_t)b * NPTS + n) * KNB;
  float xn0 = Pb[n * 3 + 0], xn1 = Pb[n * 3 + 1], xn2 = Pb[n * 3 + 2];
  float xn = xxb[n];
  int mb = lane * 4;
  unsigned vh[32];
#pragma unroll
  for (int t4 = 0; t4 < 8; ++t4) {
    int m0 = t4 * 256 + mb;
    const float* pm = Pb + (size_t)m0 * 3;
    float4 f0 = *(const float4*)(pm + 0);   // p0.xyz p1.x
    float4 f1 = *(const float4*)(pm + 4);   // p1.yz  p2.xy
    float4 f2 = *(const float4*)(pm + 8);   // p2.z   p3.xyz
    float4 xv = *(const float4*)(xxb + m0);
    float d0 = fmaf(xn2, f0.z, fmaf(xn1, f0.y, fmaf(xn0, f0.x, 0.f)));
    float d1 = fmaf(xn2, f1.y, fmaf(xn1, f1.x, fmaf(xn0, f0.w, 0.f)));
    float d2 = fmaf(xn2, f2.x, fmaf(xn1, f1.w, fmaf(xn0, f1.z, 0.f)));
    float d3 = fmaf(xn2, f2.w, fmaf(xn1, f2.z, fmaf(xn0, f2.y, 0.f)));
    vh[t4 * 4 + 0] = ordf(2.f * d0 - xn - xv.x);
    vh[t4 * 4 + 1] = ordf(2.f * d1 - xn - xv.y);
    vh[t4 * 4 + 2] = ordf(2.f * d2 - xn - xv.z);
    vh[t4 * 4 + 3] = ordf(2.f * d3 - xn - xv.w);
  }
  topk_sel_c(vh, lane, idxb);
}

// ======================================================================
// gather neighbors v3 (R12): int4 index prefetch KEPT (R11's gather
// improved 49 -> <45us; the 20 Y-row load streams are address-independent).
// Pbuf layout REVERTED to R10 channel-major: R11's block-major write made
// k_redstats reads stride-O (one 8B touch per line, 16x amplification)
// and cost ~+25us net — Pbuf is L2/L3-resident so the write pattern never
// hit HBM in the first place.  Accumulation order unchanged -> bit-identical.
// ======================================================================
__global__ void k_gather(const float* __restrict__ YS, int twoO, int O,
                         const int* __restrict__ idx,
                         float* __restrict__ hmax, float* __restrict__ hmin,
                         double* __restrict__ Pbuf, double* __restrict__ Qbuf) {
  __shared__ float ps[4][256];
  __shared__ float pq[4][256];
  int tid = threadIdx.x, w = tid >> 6, lane = tid & 63;
  int i = blockIdx.x * 4 + w;
  int b = i / NPTS;
  int Q = O >> 6;  // 1,1,2,4
  float s[4], hx[4], hn[4], sm[4], sq[4];
  const float* Srow = YS + (size_t)i * twoO + O;
#pragma unroll
  for (int q = 0; q < 4; ++q) {
    if (q < Q) s[q] = Srow[lane + 64 * q];
    hx[q] = -__builtin_inff(); hn[q] = __builtin_inff(); sm[q] = 0.f; sq[q] = 0.f;
  }
  const int* ip = idx + (size_t)i * KNB;  // 80B, 16B-aligned (20*4*i % 16 == 0)
  int4 iv0 = *(const int4*)(ip + 0);
  int4 iv1 = *(const int4*)(ip + 4);
  int4 iv2 = *(const int4*)(ip + 8);
  int4 iv3 = *(const int4*)(ip + 12);
  int4 iv4 = *(const int4*)(ip + 16);
  int mm[20] = {iv0.x, iv0.y, iv0.z, iv0.w, iv1.x, iv1.y, iv1.z, iv1.w,
                iv2.x, iv2.y, iv2.z, iv2.w, iv3.x, iv3.y, iv3.z, iv3.w,
                iv4.x, iv4.y, iv4.z, iv4.w};
#pragma unroll
  for (int k = 0; k < KNB; ++k) {
    int m = mm[k];
    const float* Yrow = YS + (size_t)(b * NPTS + m) * twoO;
#pragma unroll
    for (int q = 0; q < 4; ++q) {
      if (q < Q) {
        float h = Yrow[lane + 64 * q] + s[q];
        hx[q] = fmaxf(hx[q], h);
        hn[q] = fminf(hn[q], h);
        sm[q] += h;
        sq[q] = fmaf(h, h, sq[q]);
      }
    }
  }
#pragma unroll
  for (int q = 0; q < 4; ++q) {
    if (q < Q) {
      int o = lane + 64 * q;
      hmax[(size_t)i * O + o] = hx[q];
      hmin[(size_t)i * O + o] = hn[q];
      ps[w][o] = sm[q];
      pq[w][o] = sq[q];
    }
  }
  __syncthreads();
  if (tid < O) {
    double t1 = (double)(ps[0][tid] + ps[1][tid] + ps[2][tid] + ps[3][tid]);
    double t2 = (double)(pq[0][tid] + pq[1][tid] + pq[2][tid] + pq[3][tid]);
    Pbuf[(size_t)tid * 2048 + blockIdx.x] = t1;
    Qbuf[(size_t)tid * 2048 + blockIdx.x] = t2;
  }
}

// ---------------- deterministic reduce of 2048 partials per channel (R10 exact)
__global__ __launch_bounds__(256) void k_redstats(const double* __restrict__ Pbuf,
                                                  const double* __restrict__ Qbuf,
                                                  const float* __restrict__ g,
                                                  const float* __restrict__ bb, float cnt,
                                                  float* __restrict__ scale,
                                                  float* __restrict__ shift) {
  __shared__ double s1[256], s2[256];
  int o = blockIdx.x, t = threadIdx.x;
  double a = 0.0, c = 0.0;
#pragma unroll
  for (int j = 0; j < 8; ++j) {
    a += Pbuf[(size_t)o * 2048 + t + 256 * j];
    c += Qbuf[(size_t)o * 2048 + t + 256 * j];
  }
  s1[t] = a; s2[t] = c;
  __syncthreads();
  for (int s = 128; s; s >>= 1) {
    if (t < s) { s1[t] += s1[t + s]; s2[t] += s2[t + s]; }
    __syncthreads();
  }
  if (t == 0) {
    double mean = s1[0] / (double)cnt;
    double var = s2[0] / (double)cnt - mean * mean;
    double sc = (double)g[o] / sqrt(var + 1e-5);
    scale[o] = (float)sc;
    shift[o] = (float)((double)bb[o] - mean * sc);
  }
}

// ---------------- apply BN+lrelu (frozen)
__global__ void k_apply(const float* __restrict__ hmax, const float* __restrict__ hmin,
                        const float* __restrict__ scale, const float* __restrict__ shift,
                        float* __restrict__ Fout, int O) {
  int t = blockIdx.x * 256 + threadIdx.x;
  int i = t / O, o = t % O;
  float sc = scale[o];
  float h = (sc >= 0.f) ? hmax[t] : hmin[t];
  float v = fmaf(sc, h, shift[o]);
  Fout[(size_t)i * 512 + o] = (v >= 0.f) ? v : 0.2f * v;
}

// ---------------- final BN partials (R10: column-split grid (64,4))
__global__ void k_fstats(const float* __restrict__ PF, double* __restrict__ Fb,
                         double* __restrict__ Qb) {
  int tid = threadIdx.x, bid = blockIdx.x;
  int o = blockIdx.y * 256 + tid;
  float sm = 0.f, sq = 0.f;
  int r0 = bid * 128;
  for (int r = 0; r < 128; ++r) {
    float v = PF[(size_t)(r0 + r) * 1024 + o];
    sm += v;
    sq = fmaf(v, v, sq);
  }
  Fb[(size_t)o * 64 + bid] = (double)sm;
  Qb[(size_t)o * 64 + bid] = (double)sq;
}

// ---------------- deterministic reduce -> sc5/sh5 (frozen)
__global__ __launch_bounds__(64) void k_red5(const double* __restrict__ Fb,
                                             const double* __restrict__ Qb,
                                             const float* __restrict__ g,
                                             const float* __restrict__ bb,
                                             float* __restrict__ sc5, float* __restrict__ sh5) {
  __shared__ double s1[64], s2[64];
  int o = blockIdx.x, t = threadIdx.x;
  s1[t] = Fb[(size_t)o * 64 + t];
  s2[t] = Qb[(size_t)o * 64 + t];
  __syncthreads();
  for (int s = 32; s; s >>= 1) {
    if (t < s) { s1[t] += s1[t + s]; s2[t] += s2[t + s]; }
    __syncthreads();
  }
  if (t == 0) {
    double cnt = (double)TOTP;
    double mean = s1[0] / cnt;
    double var = s2[0] / cnt - mean * mean;
    double sc = (double)g[o] / sqrt(var + 1e-5);
    sc5[o] = (float)sc;
    sh5[o] = (float)((double)bb[o] - mean * sc);
  }
}

// ---------------- out0 (frozen)
__global__ void k_out0(const float* __restrict__ PF, const float* __restrict__ sc5,
                       const float* __restrict__ sh5, float* __restrict__ out0) {
  __shared__ float t[64][65];
  int b = blockIdx.z, p0 = blockIdx.y * 64, o0 = blockIdx.x * 64;
  int ol = threadIdx.x & 63, pg = threadIdx.x >> 6;
#pragma unroll
  for (int q = 0; q < 16; ++q) {
    int p = q * 4 + pg;
    t[p][ol] = PF[((size_t)(b * NPTS + p0 + p)) * 1024 + o0 + ol];
  }
  __syncthreads();
#pragma unroll
  for (int q = 0; q < 16; ++q) {
    int oo = q * 4 + pg;
    int o = o0 + oo;
    float v = fmaf(sc5[o], t[ol][oo], sh5[o]);
    float a = (v >= 0.f) ? v : 0.2f * v;
    out0[((size_t)(b * 1024 + o)) * 128 + p0 + ol] = a;
  }
}

// ---------------- per-(b,nb,o) max (frozen)
__global__ void k_gmax(const float* __restrict__ PF, const float* __restrict__ sc5,
                       const float* __restrict__ sh5, float* __restrict__ tmpmax) {
  int b = blockIdx.z, nb = blockIdx.y;
  int o = blockIdx.x * 256 + threadIdx.x;
  const float* base = PF + ((size_t)(b * NPTS + nb * 128)) * 1024 + o;
  float sc = sc5[o], sh = sh5[o];
  float m0 = -__builtin_inff(), m1 = m0, m2 = m0, m3 = m0;
  for (int p = 0; p < 128; p += 4) {
    float v0 = base[(size_t)(p + 0) * 1024];
    float v1 = base[(size_t)(p + 1) * 1024];
    float v2 = base[(size_t)(p + 2) * 1024];
    float v3 = base[(size_t)(p + 3) * 1024];
    float a0 = fmaf(sc, v0, sh); a0 = (a0 >= 0.f) ? a0 : 0.2f * a0;
    float a1 = fmaf(sc, v1, sh); a1 = (a1 >= 0.f) ? a1 : 0.2f * a1;
    float a2 = fmaf(sc, v2, sh); a2 = (a2 >= 0.f) ? a2 : 0.2f * a2;
    float a3 = fmaf(sc, v3, sh); a3 = (a3 >= 0.f) ? a3 : 0.2f * a3;
    m0 = fmaxf(m0, a0); m1 = fmaxf(m1, a1);
    m2 = fmaxf(m2, a2); m3 = fmaxf(m3, a3);
  }
  tmpmax[(size_t)(b * 16 + nb) * 1024 + o] = fmaxf(fmaxf(m0, m1), fmaxf(m2, m3));
}

// ---------------- gout duplication (frozen)
__global__ void k_gdup(const float* __restrict__ tmpmax, float* __restrict__ gout) {
  __shared__ float t[16][65];
  int b = blockIdx.y, o0 = blockIdx.x * 64;
  int ol = threadIdx.x & 63, ng = threadIdx.x >> 6;
#pragma unroll
  for (int q = 0; q < 4; ++q) {
    int nb = q * 4 + ng;
    t[nb][ol] = tmpmax[(size_t)(b * 16 + nb) * 1024 + o0 + ol];
  }
  __syncthreads();
  int nb2 = threadIdx.x & 15, og = threadIdx.x >> 4;
#pragma unroll
  for (int q = 0; q < 4; ++q) {
    int oo = q * 16 + og;
    float v = t[nb2][oo];
    size_t base = ((size_t)(b * 2048) + o0 + oo) * 16 + nb2;
    gout[base] = v;
    gout[base + 1024 * 16] = v;
  }
}

extern "C" void kernel_launch(void* const* d_in, const int* in_sizes, int n_in,
                              void* d_out, int out_size, void* d_ws, size_t ws_size,
                              hipStream_t stream) {
  const float* x  = (const float*)d_in[0];
  const float* W1 = (const float*)d_in[1];
  const float* W2 = (const float*)d_in[2];
  const float* W3 = (const float*)d_in[3];
  const float* W4 = (const float*)d_in[4];
  const float* W5 = (const float*)d_in[5];
  const float* g1 = (const float*)d_in[6];  const float* b1 = (const float*)d_in[7];
  const float* g2 = (const float*)d_in[8];  const float* b2 = (const float*)d_in[9];
  const float* g3 = (const float*)d_in[10]; const float* b3 = (const float*)d_in[11];
  const float* g4 = (const float*)d_in[12]; const float* b4 = (const float*)d_in[13];
  const float* g5 = (const float*)d_in[14]; const float* b5 = (const float*)d_in[15];

  float* ws = (float*)d_ws;
  size_t off = 0;
  auto alloc = [&](size_t nfl) { float* p = ws + off; off += (nfl + 63) & ~(size_t)63; return p; };
  float*  P0   = alloc((size_t)TOTP * 3);
  float*  F    = alloc((size_t)TOTP * 512);
  float*  xx   = alloc(TOTP);
  // Union U (16.78M floats): G4 lives during gram+topk of layers 2-4;
  // YS/hmax/hmin live during gemm..apply; PF lives after the last topk.
  // During the final GEMM, U[0 .. 8.39M floats) (ex-YS/hmax/hmin) is dead
  // and is reused for the pre-swizzled split-bf16 tiles (18.9 MB < 33.5 MB).
  float*  U    = alloc((size_t)BN_ * NPTS * NPTS);
  float*  G4   = U;
  float*  YS   = U;
  float*  hmax = U + (size_t)TOTP * 512;
  float*  hmin = hmax + (size_t)TOTP * 256;
  float*  PF   = hmin + (size_t)TOTP * 256;
  float*  tmpmax = alloc((size_t)BN_ * 16 * 1024);
  double* Pbuf = (double*)alloc((size_t)256 * 2048 * 2);
  double* Qbuf = (double*)alloc((size_t)256 * 2048 * 2);
  double* Fb   = (double*)alloc((size_t)1024 * 64 * 2);
  double* Qb   = (double*)alloc((size_t)1024 * 64 * 2);
  float*  scale= alloc(256);
  float*  shift= alloc(256);
  float*  sc5  = alloc(1024);
  float*  sh5  = alloc(1024);
  int*    idx  = (int*)alloc((size_t)TOTP * KNB);

  k_transpose<<<32, 256, 0, stream>>>(x, P0);

  struct L { const float* base; int lda, C, O, colout; const float* W; const float* g; const float* b; };
  L Ls[4] = {
    {P0,      3,   3,   64,  0,   W1, g1, b1},
    {F,       512, 64,  64,  64,  W2, g2, b2},
    {F + 64,  512, 64,  128, 128, W3, g3, b3},
    {F + 128, 512, 128, 256, 256, W4, g4, b4},
  };

  for (int l = 0; l < 4; ++l) {
    const L& a = Ls[l];
    k_sqnorm<<<32, 256, 0, stream>>>(a.base, a.lda, a.C, xx);
    if (l == 0) {
      k_topk3<<<dim3(512, BN_), 256, 0, stream>>>(P0, xx, idx);
    } else {
      k_gram64<<<dim3(528, 1, BN_), 256, 0, stream>>>(a.base, a.lda, a.C, G4);
      k_topk<<<dim3(512, BN_), 256, 0, stream>>>(G4, xx, idx);
    }
    int twoO = 2 * a.O;
    k_gemm64<<<dim3(twoO / 64, TOTP / 64), 256, 0, stream>>>(
        a.base, a.lda, a.C, a.W, 1, a.O, 2 * a.C, YS, twoO);
    k_gather<<<TOTP / 4, 256, 0, stream>>>(YS, twoO, a.O, idx, hmax, hmin, Pbuf, Qbuf);
    k_redstats<<<a.O, 256, 0, stream>>>(Pbuf, Qbuf, a.g, a.b, (float)(BN_ * NPTS * KNB),
                                        scale, shift);
    k_apply<<<TOTP * a.O / 256, 256, 0, stream>>>(hmax, hmin, scale, shift, F + a.colout, a.O);
  }

  // final: PF = F(8192x512) * W5^T(512x1024) via split-bf16 3-pass MFMA
  // pre-swizzled hi/lo tiles live in the dead YS/hmax/hmin region of U
  u16* FhT = (u16*)U;                       // 8192x512 -> 1024 tiles * 8KB
  u16* FlT = FhT + (size_t)4194304;
  u16* WhT = FlT + (size_t)4194304;         // 1024x512 -> 128 tiles * 8KB
  u16* WlT = WhT + (size_t)524288;
  k_split_swz<<<2048, 256, 0, stream>>>(F, FhT, FlT);
  k_split_swz<<<256, 256, 0, stream>>>(W5, WhT, WlT);
  k_gemm_mfma<<<dim3(8, 64), 256, 0, stream>>>(FhT, FlT, WhT, WlT, PF);

  k_fstats<<<dim3(64, 4), 256, 0, stream>>>(PF, Fb, Qb);
  k_red5<<<1024, 64, 0, stream>>>(Fb, Qb, g5, b5, sc5, sh5);

  float* out0 = (float*)d_out;
  float* gout = out0 + (size_t)BN_ * 1024 * 128;
  k_out0<<<dim3(16, 2, BN_), 256, 0, stream>>>(PF, sc5, sh5, out0);
  k_gmax<<<dim3(4, 16, BN_), 256, 0, stream>>>(PF, sc5, sh5, tmpmax);
  k_gdup<<<dim3(16, BN_), 256, 0, stream>>>(tmpmax, gout);
}

// Round 13
// 600.039 us; speedup vs baseline: 1.0538x; 1.0016x over previous
//
#include <hip/hip_runtime.h>
#include <cstdint>
#include <cmath>

#define BN_ 4
#define NPTS 2048
#define KNB 20
#define TOTP (BN_ * NPTS)   // 8192

typedef unsigned short u16;
typedef unsigned long long u64;
typedef short bf16x8 __attribute__((ext_vector_type(8)));
typedef u16 u16x8 __attribute__((ext_vector_type(8)));
typedef float f32x4 __attribute__((ext_vector_type(4)));

// ---------------- transpose x (B,3,N) -> P0 (B*N, 3)
__global__ void k_transpose(const float* __restrict__ x, float* __restrict__ P0) {
  int i = blockIdx.x * 256 + threadIdx.x;
  if (i >= TOTP) return;
  int b = i / NPTS, n = i % NPTS;
#pragma unroll
  for (int c = 0; c < 3; ++c)
    P0[i * 3 + c] = x[((size_t)b * 3 + c) * NPTS + n];
}

// ---------------- squared norms per point
__global__ void k_sqnorm(const float* __restrict__ base, int ld, int C, float* __restrict__ xx) {
  int i = blockIdx.x * 256 + threadIdx.x;
  if (i >= TOTP) return;
  const float* r = base + (size_t)i * ld;
  float s = 0.f;
  for (int c = 0; c < C; ++c) s = fmaf(r[c], r[c], s);
  xx[i] = s;
}

// ======================================================================
// Symmetric Gram: 64x64 tiles, __launch_bounds__(256,4).  (R10 proven:
// LDS-transposed mirror write -> contiguous 256B rows.)
// ======================================================================
__global__ __launch_bounds__(256, 4) void k_gram64(const float* __restrict__ A_all, int lda,
                                                   int K, float* __restrict__ G4) {
  __shared__ float As[2][8][64];
  __shared__ float Bs[2][8][64];
  __shared__ float tb[64][68];  // [col_local][row_local], row stride 272B (16B-aligned)
  const int T = NPTS / 64;  // 32
  int q = blockIdx.x;
  int bi = 0;
  while (q >= T - bi) { q -= T - bi; ++bi; }
  int bj = bi + q;
  int b = blockIdx.z;
  const float* A = A_all + (size_t)b * NPTS * lda;
  float* G = G4 + (size_t)b * NPTS * NPTS;
  int tid = threadIdx.x;
  int i0 = bi * 64, m0 = bj * 64;
  int tx = tid & 15, ty = tid >> 4;
  int lr = tid >> 2;          // 0..63
  int lc = (tid & 3) * 2;     // 0,2,4,6
  const float* Arow = A + (size_t)(i0 + lr) * lda;
  const float* Brow = A + (size_t)(m0 + lr) * lda;
  float acc[4][4] = {};
  float2 pa, pb;

  pa = *(const float2*)(Arow + lc);
  pb = *(const float2*)(Brow + lc);
  As[0][lc + 0][lr] = pa.x; As[0][lc + 1][lr] = pa.y;
  Bs[0][lc + 0][lr] = pb.x; Bs[0][lc + 1][lr] = pb.y;
  __syncthreads();
  for (int k0 = 0; k0 < K; k0 += 8) {
    int cur = (k0 >> 3) & 1;
    bool more = (k0 + 8 < K);
    if (more) {
      pa = *(const float2*)(Arow + k0 + 8 + lc);
      pb = *(const float2*)(Brow + k0 + 8 + lc);
    }
#pragma unroll
    for (int k = 0; k < 8; ++k) {
      float4 a0 = *(const float4*)&As[cur][k][ty * 4];
      float4 b0 = *(const float4*)&Bs[cur][k][tx * 4];
      float ar[4] = {a0.x, a0.y, a0.z, a0.w};
      float br[4] = {b0.x, b0.y, b0.z, b0.w};
#pragma unroll
      for (int ii = 0; ii < 4; ++ii)
#pragma unroll
        for (int jj = 0; jj < 4; ++jj)
          acc[ii][jj] = fmaf(ar[ii], br[jj], acc[ii][jj]);
    }
    if (more) {
      int nxt = cur ^ 1;
      As[nxt][lc + 0][lr] = pa.x; As[nxt][lc + 1][lr] = pa.y;
      Bs[nxt][lc + 0][lr] = pb.x; Bs[nxt][lc + 1][lr] = pb.y;
    }
    __syncthreads();
  }
#pragma unroll
  for (int ii = 0; ii < 4; ++ii) {
    int row = i0 + ty * 4 + ii;
    float4 vv = {acc[ii][0], acc[ii][1], acc[ii][2], acc[ii][3]};
    *(float4*)(G + (size_t)row * NPTS + m0 + tx * 4) = vv;
  }
  if (bi != bj) {
    // stage transposed: tb[col_local][row_local] = acc[row_l][col_l]
#pragma unroll
    for (int jj = 0; jj < 4; ++jj) {
      float4 vv = {acc[0][jj], acc[1][jj], acc[2][jj], acc[3][jj]};
      *(float4*)&tb[tx * 4 + jj][ty * 4] = vv;
    }
    __syncthreads();
    int cl0 = tid >> 4;        // 0..15
    int cc = (tid & 15) * 4;   // 0..60
#pragma unroll
    for (int qq = 0; qq < 4; ++qq) {
      int cl = qq * 16 + cl0;
      float4 vv = *(const float4*)&tb[cl][cc];
      *(float4*)(G + (size_t)(m0 + cl) * NPTS + i0 + cc) = vv;  // 256B-contig rows
    }
  }
}

// ======================================================================
// Final GEMM via split-bf16 (hi/lo) 3-pass MFMA (R0 proven).
// ======================================================================

__device__ __forceinline__ u16 bf16_rn(float f) {
  unsigned u = __float_as_uint(f);
  unsigned r = u + 0x7fffu + ((u >> 16) & 1u);
  return (u16)(r >> 16);
}

// one thread per 8-element k-chunk; src is row-major [rows][512]
__global__ __launch_bounds__(256) void k_split_swz(const float* __restrict__ src,
                                                   u16* __restrict__ dh,
                                                   u16* __restrict__ dl) {
  int c = blockIdx.x * 256 + threadIdx.x;
  int row = c >> 6;            // 64 chunks per row (512/8)
  int k0 = (c & 63) << 3;      // 0..504
  const float4* s = (const float4*)(src + (size_t)row * 512 + k0);
  float4 v0 = s[0], v1 = s[1];
  float vv[8] = {v0.x, v0.y, v0.z, v0.w, v1.x, v1.y, v1.z, v1.w};
  u16x8 hv, lv;
#pragma unroll
  for (int e = 0; e < 8; ++e) {
    u16 h = bf16_rn(vv[e]);
    float fh = __uint_as_float((unsigned)h << 16);
    hv[e] = h;
    lv[e] = bf16_rn(vv[e] - fh);
  }
  int tr = row >> 7, rloc = row & 127, tk = k0 >> 5, ss = (k0 >> 3) & 3;
  size_t tb = ((size_t)(tr * 16 + tk)) * 4096;  // tile base in u16 units (8KB)
  unsigned P = ((unsigned)(rloc * 64 + ss * 16)) ^ (((unsigned)(rloc & 7)) << 4);
  *(u16x8*)(dh + tb + (P >> 1)) = hv;
  *(u16x8*)(dl + tb + (P >> 1)) = lv;
}

__device__ __forceinline__ void gl2lds16(const void* g, void* l) {
  __builtin_amdgcn_global_load_lds(
      (const __attribute__((address_space(1))) unsigned int*)g,
      (__attribute__((address_space(3))) unsigned int*)l, 16, 0, 0);
}

#define MFMA16(A, B, C) __builtin_amdgcn_mfma_f32_16x16x32_bf16(A, B, C, 0, 0, 0)

__global__ __launch_bounds__(256, 2) void k_gemm_mfma(
    const u16* __restrict__ AhT, const u16* __restrict__ AlT,
    const u16* __restrict__ BhT, const u16* __restrict__ BlT,
    float* __restrict__ Cout) {
  // block: 128x128 tile; 4 waves, each 64x64 (4x4 frags of 16x16); BK=32
  __shared__ u16 lds[2][4][4096];  // [buf][Ah,Al,Bh,Bl][8KB tile]  = 64 KB
  int tid = threadIdx.x;
  int w = tid >> 6, lane = tid & 63;
  int wr = w >> 1, wc = w & 1;
  int fr = lane & 15, fs = lane >> 4;

  size_t tbA = (size_t)blockIdx.y * 16 * 4096;  // u16 units
  size_t tbB = (size_t)blockIdx.x * 16 * 4096;
  int lo0 = w * 512 + lane * 8;  // u16 offset of this lane's 16B chunk
  int lo1 = 2048 + lo0;

  auto stage = [&](int buf, int t) {
    size_t oA = tbA + (size_t)t * 4096;
    size_t oB = tbB + (size_t)t * 4096;
    gl2lds16(AhT + oA + lo0, &lds[buf][0][lo0]);
    gl2lds16(AhT + oA + lo1, &lds[buf][0][lo1]);
    gl2lds16(AlT + oA + lo0, &lds[buf][1][lo0]);
    gl2lds16(AlT + oA + lo1, &lds[buf][1][lo1]);
    gl2lds16(BhT + oB + lo0, &lds[buf][2][lo0]);
    gl2lds16(BhT + oB + lo1, &lds[buf][2][lo1]);
    gl2lds16(BlT + oB + lo0, &lds[buf][3][lo0]);
    gl2lds16(BlT + oB + lo1, &lds[buf][3][lo1]);
  };

  // fragment byte offsets (same XOR as the pre-swizzled tiles)
  unsigned aoff = ((unsigned)((wr * 64 + fr) * 64 + fs * 16)) ^ (((unsigned)(fr & 7)) << 4);
  unsigned boff = ((unsigned)((wc * 64 + fr) * 64 + fs * 16)) ^ (((unsigned)(fr & 7)) << 4);

  f32x4 acc[4][4] = {};

  stage(0, 0);
  __syncthreads();
#pragma unroll 1
  for (int t = 0; t < 16; ++t) {
    int cur = t & 1;
    if (t < 15) stage(cur ^ 1, t + 1);
    bf16x8 ah[4], al[4], bh[4], bl[4];
#pragma unroll
    for (int m = 0; m < 4; ++m) {
      ah[m] = *(const bf16x8*)((const char*)&lds[cur][0][0] + aoff + m * 1024);
      al[m] = *(const bf16x8*)((const char*)&lds[cur][1][0] + aoff + m * 1024);
    }
#pragma unroll
    for (int n = 0; n < 4; ++n) {
      bh[n] = *(const bf16x8*)((const char*)&lds[cur][2][0] + boff + n * 1024);
      bl[n] = *(const bf16x8*)((const char*)&lds[cur][3][0] + boff + n * 1024);
    }
#pragma unroll
    for (int m = 0; m < 4; ++m)
#pragma unroll
      for (int n = 0; n < 4; ++n) {
        acc[m][n] = MFMA16(ah[m], bh[n], acc[m][n]);
        acc[m][n] = MFMA16(ah[m], bl[n], acc[m][n]);
        acc[m][n] = MFMA16(al[m], bh[n], acc[m][n]);
      }
    __syncthreads();
  }
  // epilogue: D frag -> PF.  row = base + fs*4 + r, col = base + fr
  int r0 = blockIdx.y * 128 + wr * 64 + fs * 4;
  int c0 = blockIdx.x * 128 + wc * 64 + fr;
#pragma unroll
  for (int m = 0; m < 4; ++m)
#pragma unroll
    for (int n = 0; n < 4; ++n)
#pragma unroll
      for (int r = 0; r < 4; ++r)
        Cout[(size_t)(r0 + m * 16 + r) * 1024 + (c0 + n * 16)] = acc[m][n][r];
}

// ======================================================================
// Layer GEMM v3 (R9 proven): 64x64 tile, 4x4 micro, VALU-balanced.
// ======================================================================
__global__ __launch_bounds__(256, 4) void k_gemm64(const float* __restrict__ A, int lda, int K,
                                                   const float* __restrict__ W, int mode, int O,
                                                   int twoC, float* __restrict__ Cout, int ldc) {
  __shared__ float As[2][8][64];
  __shared__ float Bs[2][8][64];
  int tid = threadIdx.x;
  int i0 = blockIdx.y * 64, j0 = blockIdx.x * 64;
  int tx = tid & 15, ty = tid >> 4;
  int lr = tid >> 2;          // 0..63: A row / W output-col
  int lc = (tid & 3) * 2;     // k pair 0,2,4,6
  const float* ArowA = A + (size_t)(i0 + lr) * lda;
  int j = j0 + lr;
  float acc[4][4] = {};

  auto stage = [&](int buf, int k0) {
    if ((lda & 1) == 0 && k0 + lc + 2 <= K) {
      float2 av = *(const float2*)(ArowA + k0 + lc);
      As[buf][lc + 0][lr] = av.x;
      As[buf][lc + 1][lr] = av.y;
    } else {
#pragma unroll
      for (int u = 0; u < 2; ++u) {
        int k = k0 + lc + u;
        As[buf][lc + u][lr] = (k < K) ? ArowA[k] : 0.f;
      }
    }
#pragma unroll
    for (int u = 0; u < 2; ++u) {
      int k = k0 + lc + u;
      float wv = 0.f;
      if (k < K) {
        if (mode == 0) wv = W[(size_t)j * K + k];
        else if (j < O) wv = W[(size_t)j * twoC + k];
        else { const float* wr = W + (size_t)(j - O) * twoC; wv = wr[K + k] - wr[k]; }
      }
      Bs[buf][lc + u][lr] = wv;
    }
  };

  stage(0, 0);
  __syncthreads();
  for (int k0 = 0; k0 < K; k0 += 8) {
    int cur = (k0 >> 3) & 1;
    if (k0 + 8 < K) stage(cur ^ 1, k0 + 8);
#pragma unroll
    for (int k = 0; k < 8; ++k) {
      float4 a0 = *(const float4*)&As[cur][k][ty * 4];
      float4 b0 = *(const float4*)&Bs[cur][k][tx * 4];
      float ar[4] = {a0.x, a0.y, a0.z, a0.w};
      float br[4] = {b0.x, b0.y, b0.z, b0.w};
#pragma unroll
      for (int ii = 0; ii < 4; ++ii)
#pragma unroll
        for (int jj = 0; jj < 4; ++jj)
          acc[ii][jj] = fmaf(ar[ii], br[jj], acc[ii][jj]);
    }
    __syncthreads();
  }
#pragma unroll
  for (int ii = 0; ii < 4; ++ii) {
    int row = i0 + ty * 4 + ii;
    float* cr = Cout + (size_t)row * ldc + j0;
    float4 vv = {acc[ii][0], acc[ii][1], acc[ii][2], acc[ii][3]};
    *(float4*)(cr + tx * 4) = vv;
  }
}

// ======================================================================
// Top-20 selection v6 (R10 proven): DS-free reduce + coalesced re-slotted
// candidate mapping m = t4*256 + lane*4 + e.
// ======================================================================

__device__ __forceinline__ unsigned ordf(float f) {
  int u = __float_as_int(f);
  return (unsigned)(u ^ ((u >> 31) | 0x80000000));
}

__device__ __forceinline__ unsigned rowmax16(unsigned v) {
  unsigned t;
  t = (unsigned)__builtin_amdgcn_update_dpp(0, (int)v, 0xB1, 0xF, 0xF, true);   // quad_perm xor1
  v = v > t ? v : t;
  t = (unsigned)__builtin_amdgcn_update_dpp(0, (int)v, 0x4E, 0xF, 0xF, true);   // quad_perm xor2
  v = v > t ? v : t;
  t = (unsigned)__builtin_amdgcn_update_dpp(0, (int)v, 0x141, 0xF, 0xF, true);  // row_half_mirror
  v = v > t ? v : t;
  t = (unsigned)__builtin_amdgcn_update_dpp(0, (int)v, 0x140, 0xF, 0xF, true);  // row_mirror
  v = v > t ? v : t;
  return v;  // all lanes of each 16-lane row hold the row max
}

__device__ __forceinline__ unsigned rowmin16(unsigned v) {
  unsigned t;
  t = (unsigned)__builtin_amdgcn_update_dpp(0, (int)v, 0xB1, 0xF, 0xF, true);
  v = v < t ? v : t;
  t = (unsigned)__builtin_amdgcn_update_dpp(0, (int)v, 0x4E, 0xF, 0xF, true);
  v = v < t ? v : t;
  t = (unsigned)__builtin_amdgcn_update_dpp(0, (int)v, 0x141, 0xF, 0xF, true);
  v = v < t ? v : t;
  t = (unsigned)__builtin_amdgcn_update_dpp(0, (int)v, 0x140, 0xF, 0xF, true);
  v = v < t ? v : t;
  return v;
}

__device__ __forceinline__ unsigned wave_max_u32(unsigned v) {
  v = rowmax16(v);
  unsigned r0 = (unsigned)__builtin_amdgcn_readlane((int)v, 0);
  unsigned r1 = (unsigned)__builtin_amdgcn_readlane((int)v, 16);
  unsigned r2 = (unsigned)__builtin_amdgcn_readlane((int)v, 32);
  unsigned r3 = (unsigned)__builtin_amdgcn_readlane((int)v, 48);
  unsigned a = r0 > r1 ? r0 : r1;
  unsigned b = r2 > r3 ? r2 : r3;
  return a > b ? a : b;  // uniform
}

__device__ __forceinline__ unsigned wave_min_u32(unsigned v) {
  v = rowmin16(v);
  unsigned r0 = (unsigned)__builtin_amdgcn_readlane((int)v, 0);
  unsigned r1 = (unsigned)__builtin_amdgcn_readlane((int)v, 16);
  unsigned r2 = (unsigned)__builtin_amdgcn_readlane((int)v, 32);
  unsigned r3 = (unsigned)__builtin_amdgcn_readlane((int)v, 48);
  unsigned a = r0 < r1 ? r0 : r1;
  unsigned b = r2 < r3 ? r2 : r3;
  return a < b ? a : b;  // uniform
}

// klo for slot t of a lane:  base - ((t>>2)*256 + (t&3)),  base = ~(lane*4)
__device__ __forceinline__ void topk_sel_c(const unsigned* __restrict__ vh, int lane,
                                           int* __restrict__ idxb) {
  unsigned base = ~(unsigned)(lane * 4);
  u64 k1 = 0, k2 = 0;
#pragma unroll
  for (int t = 0; t < 32; ++t) {
    u64 key = ((u64)vh[t] << 32) | (unsigned)(base - ((t >> 2) * 256 + (t & 3)));
    if (key > k1) { k2 = k1; k1 = key; }
    else if (key > k2) { k2 = key; }
  }
  unsigned rm = 0;  // removal bitmask over local slots t
  for (int r = 0; r < KNB; ++r) {
    unsigned o1 = (unsigned)(k1 >> 32);
    unsigned g = wave_max_u32(o1);
    bool matched = (o1 == g);
    u64 bal = __ballot(matched);
    unsigned m1 = ~(unsigned)k1;
    unsigned m_win;
    if (__popcll(bal) == 1) {
      int src = (int)(__ffsll((long long)bal) - 1);
      m_win = (unsigned)__builtin_amdgcn_readlane((int)m1, src);
    } else {
      // exact value tie across lanes: min index wins (rare)
      m_win = wave_min_u32(matched ? m1 : 0xFFFFFFFFu);
    }
    if (lane == 0) idxb[r] = (int)m_win;
    bool mine = matched && (m1 == m_win);
    if (mine) {
      rm |= 1u << (((m_win >> 8) << 2) | (m_win & 3));  // local slot of consumed key
      k1 = k2;
      k2 = 0;
    }
    if (__any(mine && k1 == 0)) {
      if (mine && k1 == 0) {
        u64 a = 0, c = 0;
#pragma unroll
        for (int t = 0; t < 32; ++t) {
          unsigned q = ((rm >> t) & 1u) ? 0u : vh[t];
          u64 key = ((u64)q << 32) | (unsigned)(base - ((t >> 2) * 256 + (t & 3)));
          if (key > a) { c = a; a = key; }
          else if (key > c) { c = key; }
        }
        k1 = a; k2 = c;
      }
    }
  }
}

// ---------------- top-20 (layers 2-4): Gram-based distances
__global__ __launch_bounds__(256) void k_topk(const float* __restrict__ G4,
                                              const float* __restrict__ xx,
                                              int* __restrict__ idx) {
  int tid = threadIdx.x, w = tid >> 6, lane = tid & 63;
  int b = blockIdx.y;
  int n = blockIdx.x * 4 + w;
  const float* Gr = G4 + (size_t)b * NPTS * NPTS + (size_t)n * NPTS;
  const float* xxb = xx + b * NPTS;
  int* idxb = idx + ((size_t)b * NPTS + n) * KNB;
  float xn = xxb[n];
  int mb = lane * 4;
  unsigned vh[32];
#pragma unroll
  for (int t4 = 0; t4 < 8; ++t4) {
    int m0 = t4 * 256 + mb;
    float4 gv = *(const float4*)(Gr + m0);
    float4 xv = *(const float4*)(xxb + m0);
    vh[t4 * 4 + 0] = ordf(2.f * gv.x - xn - xv.x);
    vh[t4 * 4 + 1] = ordf(2.f * gv.y - xn - xv.y);
    vh[t4 * 4 + 2] = ordf(2.f * gv.z - xn - xv.z);
    vh[t4 * 4 + 3] = ordf(2.f * gv.w - xn - xv.w);
  }
  topk_sel_c(vh, lane, idxb);
}

// ---------------- top-20 for layer 1 (K=3): direct distance
__global__ __launch_bounds__(256) void k_topk3(const float* __restrict__ P0,
                                               const float* __restrict__ xx,
                                               int* __restrict__ idx) {
  int tid = threadIdx.x, w = tid >> 6, lane = tid & 63;
  int b = blockIdx.y;
  int n = blockIdx.x * 4 + w;
  const float* Pb = P0 + (size_t)b * NPTS * 3;
  const float* xxb = xx + b * NPTS;
  int* idxb = idx + ((size_t)b * NPTS + n) * KNB;
  float xn0 = Pb[n * 3 + 0], xn1 = Pb[n * 3 + 1], xn2 = Pb[n * 3 + 2];
  float xn = xxb[n];
  int mb = lane * 4;
  unsigned vh[32];
#pragma unroll
  for (int t4 = 0; t4 < 8; ++t4) {
    int m0 = t4 * 256 + mb;
    const float* pm = Pb + (size_t)m0 * 3;
    float4 f0 = *(const float4*)(pm + 0);   // p0.xyz p1.x
    float4 f1 = *(const float4*)(pm + 4);   // p1.yz  p2.xy
    float4 f2 = *(const float4*)(pm + 8);   // p2.z   p3.xyz
    float4 xv = *(const float4*)(xxb + m0);
    float d0 = fmaf(xn2, f0.z, fmaf(xn1, f0.y, fmaf(xn0, f0.x, 0.f)));
    float d1 = fmaf(xn2, f1.y, fmaf(xn1, f1.x, fmaf(xn0, f0.w, 0.f)));
    float d2 = fmaf(xn2, f2.x, fmaf(xn1, f1.w, fmaf(xn0, f1.z, 0.f)));
    float d3 = fmaf(xn2, f2.w, fmaf(xn1, f2.z, fmaf(xn0, f2.y, 0.f)));
    vh[t4 * 4 + 0] = ordf(2.f * d0 - xn - xv.x);
    vh[t4 * 4 + 1] = ordf(2.f * d1 - xn - xv.y);
    vh[t4 * 4 + 2] = ordf(2.f * d2 - xn - xv.z);
    vh[t4 * 4 + 3] = ordf(2.f * d3 - xn - xv.w);
  }
  topk_sel_c(vh, lane, idxb);
}

// ======================================================================
// gather neighbors v4 (R13): int4 index prefetch (R12 proven) + single
// extreme buffer.  sign(scale) == sign(g[o]) exactly (scale = g/sqrt(var),
// sqrt>0), and g is available BEFORE gather — so store only
// hsel = (g[o]>=0) ? max : min into the hmax buffer and drop the hmin
// write entirely (halves extreme write traffic; apply's read halves too).
// Old behavior selected by sc>=0; differs only when sc==+/-0 (underflow),
// where v = fmaf(+/-0,h,shift) is h-independent to within +/-0.
// Accumulation chains unchanged.
// ======================================================================
__global__ void k_gather(const float* __restrict__ YS, int twoO, int O,
                         const int* __restrict__ idx, const float* __restrict__ gvec,
                         float* __restrict__ hsel,
                         double* __restrict__ Pbuf, double* __restrict__ Qbuf) {
  __shared__ float ps[4][256];
  __shared__ float pq[4][256];
  int tid = threadIdx.x, w = tid >> 6, lane = tid & 63;
  int i = blockIdx.x * 4 + w;
  int b = i / NPTS;
  int Q = O >> 6;  // 1,1,2,4
  float s[4], hx[4], hn[4], sm[4], sq[4];
  const float* Srow = YS + (size_t)i * twoO + O;
#pragma unroll
  for (int q = 0; q < 4; ++q) {
    if (q < Q) s[q] = Srow[lane + 64 * q];
    hx[q] = -__builtin_inff(); hn[q] = __builtin_inff(); sm[q] = 0.f; sq[q] = 0.f;
  }
  const int* ip = idx + (size_t)i * KNB;  // 80B, 16B-aligned (20*4*i % 16 == 0)
  int4 iv0 = *(const int4*)(ip + 0);
  int4 iv1 = *(const int4*)(ip + 4);
  int4 iv2 = *(const int4*)(ip + 8);
  int4 iv3 = *(const int4*)(ip + 12);
  int4 iv4 = *(const int4*)(ip + 16);
  int mm[20] = {iv0.x, iv0.y, iv0.z, iv0.w, iv1.x, iv1.y, iv1.z, iv1.w,
                iv2.x, iv2.y, iv2.z, iv2.w, iv3.x, iv3.y, iv3.z, iv3.w,
                iv4.x, iv4.y, iv4.z, iv4.w};
#pragma unroll
  for (int k = 0; k < KNB; ++k) {
    int m = mm[k];
    const float* Yrow = YS + (size_t)(b * NPTS + m) * twoO;
#pragma unroll
    for (int q = 0; q < 4; ++q) {
      if (q < Q) {
        float h = Yrow[lane + 64 * q] + s[q];
        hx[q] = fmaxf(hx[q], h);
        hn[q] = fminf(hn[q], h);
        sm[q] += h;
        sq[q] = fmaf(h, h, sq[q]);
      }
    }
  }
#pragma unroll
  for (int q = 0; q < 4; ++q) {
    if (q < Q) {
      int o = lane + 64 * q;
      hsel[(size_t)i * O + o] = (gvec[o] >= 0.f) ? hx[q] : hn[q];
      ps[w][o] = sm[q];
      pq[w][o] = sq[q];
    }
  }
  __syncthreads();
  if (tid < O) {
    double t1 = (double)(ps[0][tid] + ps[1][tid] + ps[2][tid] + ps[3][tid]);
    double t2 = (double)(pq[0][tid] + pq[1][tid] + pq[2][tid] + pq[3][tid]);
    Pbuf[(size_t)tid * 2048 + blockIdx.x] = t1;
    Qbuf[(size_t)tid * 2048 + blockIdx.x] = t2;
  }
}

// ---------------- deterministic reduce of 2048 partials per channel (R10 exact)
__global__ __launch_bounds__(256) void k_redstats(const double* __restrict__ Pbuf,
                                                  const double* __restrict__ Qbuf,
                                                  const float* __restrict__ g,
                                                  const float* __restrict__ bb, float cnt,
                                                  float* __restrict__ scale,
                                                  float* __restrict__ shift) {
  __shared__ double s1[256], s2[256];
  int o = blockIdx.x, t = threadIdx.x;
  double a = 0.0, c = 0.0;
#pragma unroll
  for (int j = 0; j < 8; ++j) {
    a += Pbuf[(size_t)o * 2048 + t + 256 * j];
    c += Qbuf[(size_t)o * 2048 + t + 256 * j];
  }
  s1[t] = a; s2[t] = c;
  __syncthreads();
  for (int s = 128; s; s >>= 1) {
    if (t < s) { s1[t] += s1[t + s]; s2[t] += s2[t + s]; }
    __syncthreads();
  }
  if (t == 0) {
    double mean = s1[0] / (double)cnt;
    double var = s2[0] / (double)cnt - mean * mean;
    double sc = (double)g[o] / sqrt(var + 1e-5);
    scale[o] = (float)sc;
    shift[o] = (float)((double)bb[o] - mean * sc);
  }
}

// ---------------- apply BN+lrelu (R13: single extreme buffer)
__global__ void k_apply(const float* __restrict__ hsel,
                        const float* __restrict__ scale, const float* __restrict__ shift,
                        float* __restrict__ Fout, int O) {
  int t = blockIdx.x * 256 + threadIdx.x;
  int i = t / O, o = t % O;
  float v = fmaf(scale[o], hsel[t], shift[o]);
  Fout[(size_t)i * 512 + o] = (v >= 0.f) ? v : 0.2f * v;
}

// ---------------- final BN partials (R10: column-split grid (64,4))
__global__ void k_fstats(const float* __restrict__ PF, double* __restrict__ Fb,
                         double* __restrict__ Qb) {
  int tid = threadIdx.x, bid = blockIdx.x;
  int o = blockIdx.y * 256 + tid;
  float sm = 0.f, sq = 0.f;
  int r0 = bid * 128;
  for (int r = 0; r < 128; ++r) {
    float v = PF[(size_t)(r0 + r) * 1024 + o];
    sm += v;
    sq = fmaf(v, v, sq);
  }
  Fb[(size_t)o * 64 + bid] = (double)sm;
  Qb[(size_t)o * 64 + bid] = (double)sq;
}

// ---------------- deterministic reduce -> sc5/sh5 (frozen)
__global__ __launch_bounds__(64) void k_red5(const double* __restrict__ Fb,
                                             const double* __restrict__ Qb,
                                             const float* __restrict__ g,
                                             const float* __restrict__ bb,
                                             float* __restrict__ sc5, float* __restrict__ sh5) {
  __shared__ double s1[64], s2[64];
  int o = blockIdx.x, t = threadIdx.x;
  s1[t] = Fb[(size_t)o * 64 + t];
  s2[t] = Qb[(size_t)o * 64 + t];
  __syncthreads();
  for (int s = 32; s; s >>= 1) {
    if (t < s) { s1[t] += s1[t + s]; s2[t] += s2[t + s]; }
    __syncthreads();
  }
  if (t == 0) {
    double cnt = (double)TOTP;
    double mean = s1[0] / cnt;
    double var = s2[0] / cnt - mean * mean;
    double sc = (double)g[o] / sqrt(var + 1e-5);
    sc5[o] = (float)sc;
    sh5[o] = (float)((double)bb[o] - mean * sc);
  }
}

// ---------------- out0 (frozen)
__global__ void k_out0(const float* __restrict__ PF, const float* __restrict__ sc5,
                       const float* __restrict__ sh5, float* __restrict__ out0) {
  __shared__ float t[64][65];
  int b = blockIdx.z, p0 = blockIdx.y * 64, o0 = blockIdx.x * 64;
  int ol = threadIdx.x & 63, pg = threadIdx.x >> 6;
#pragma unroll
  for (int q = 0; q < 16; ++q) {
    int p = q * 4 + pg;
    t[p][ol] = PF[((size_t)(b * NPTS + p0 + p)) * 1024 + o0 + ol];
  }
  __syncthreads();
#pragma unroll
  for (int q = 0; q < 16; ++q) {
    int oo = q * 4 + pg;
    int o = o0 + oo;
    float v = fmaf(sc5[o], t[ol][oo], sh5[o]);
    float a = (v >= 0.f) ? v : 0.2f * v;
    out0[((size_t)(b * 1024 + o)) * 128 + p0 + ol] = a;
  }
}

// ---------------- per-(b,nb,o) max (frozen)
__global__ void k_gmax(const float* __restrict__ PF, const float* __restrict__ sc5,
                       const float* __restrict__ sh5, float* __restrict__ tmpmax) {
  int b = blockIdx.z, nb = blockIdx.y;
  int o = blockIdx.x * 256 + threadIdx.x;
  const float* base = PF + ((size_t)(b * NPTS + nb * 128)) * 1024 + o;
  float sc = sc5[o], sh = sh5[o];
  float m0 = -__builtin_inff(), m1 = m0, m2 = m0, m3 = m0;
  for (int p = 0; p < 128; p += 4) {
    float v0 = base[(size_t)(p + 0) * 1024];
    float v1 = base[(size_t)(p + 1) * 1024];
    float v2 = base[(size_t)(p + 2) * 1024];
    float v3 = base[(size_t)(p + 3) * 1024];
    float a0 = fmaf(sc, v0, sh); a0 = (a0 >= 0.f) ? a0 : 0.2f * a0;
    float a1 = fmaf(sc, v1, sh); a1 = (a1 >= 0.f) ? a1 : 0.2f * a1;
    float a2 = fmaf(sc, v2, sh); a2 = (a2 >= 0.f) ? a2 : 0.2f * a2;
    float a3 = fmaf(sc, v3, sh); a3 = (a3 >= 0.f) ? a3 : 0.2f * a3;
    m0 = fmaxf(m0, a0); m1 = fmaxf(m1, a1);
    m2 = fmaxf(m2, a2); m3 = fmaxf(m3, a3);
  }
  tmpmax[(size_t)(b * 16 + nb) * 1024 + o] = fmaxf(fmaxf(m0, m1), fmaxf(m2, m3));
}

// ---------------- gout duplication (frozen)
__global__ void k_gdup(const float* __restrict__ tmpmax, float* __restrict__ gout) {
  __shared__ float t[16][65];
  int b = blockIdx.y, o0 = blockIdx.x * 64;
  int ol = threadIdx.x & 63, ng = threadIdx.x >> 6;
#pragma unroll
  for (int q = 0; q < 4; ++q) {
    int nb = q * 4 + ng;
    t[nb][ol] = tmpmax[(size_t)(b * 16 + nb) * 1024 + o0 + ol];
  }
  __syncthreads();
  int nb2 = threadIdx.x & 15, og = threadIdx.x >> 4;
#pragma unroll
  for (int q = 0; q < 4; ++q) {
    int oo = q * 16 + og;
    float v = t[nb2][oo];
    size_t base = ((size_t)(b * 2048) + o0 + oo) * 16 + nb2;
    gout[base] = v;
    gout[base + 1024 * 16] = v;
  }
}

extern "C" void kernel_launch(void* const* d_in, const int* in_sizes, int n_in,
                              void* d_out, int out_size, void* d_ws, size_t ws_size,
                              hipStream_t stream) {
  const float* x  = (const float*)d_in[0];
  const float* W1 = (const float*)d_in[1];
  const float* W2 = (const float*)d_in[2];
  const float* W3 = (const float*)d_in[3];
  const float* W4 = (const float*)d_in[4];
  const float* W5 = (const float*)d_in[5];
  const float* g1 = (const float*)d_in[6];  const float* b1 = (const float*)d_in[7];
  const float* g2 = (const float*)d_in[8];  const float* b2 = (const float*)d_in[9];
  const float* g3 = (const float*)d_in[10]; const float* b3 = (const float*)d_in[11];
  const float* g4 = (const float*)d_in[12]; const float* b4 = (const float*)d_in[13];
  const float* g5 = (const float*)d_in[14]; const float* b5 = (const float*)d_in[15];

  float* ws = (float*)d_ws;
  size_t off = 0;
  auto alloc = [&](size_t nfl) { float* p = ws + off; off += (nfl + 63) & ~(size_t)63; return p; };
  float*  P0   = alloc((size_t)TOTP * 3);
  float*  F    = alloc((size_t)TOTP * 512);
  float*  xx   = alloc(TOTP);
  // Union U (16.78M floats): G4 lives during gram+topk of layers 2-4;
  // YS/hsel live during gemm..apply; PF lives after the last topk.
  float*  U    = alloc((size_t)BN_ * NPTS * NPTS);
  float*  G4   = U;
  float*  YS   = U;
  float*  hsel = U + (size_t)TOTP * 512;
  float*  PF   = hsel + (size_t)TOTP * 512;
  float*  tmpmax = alloc((size_t)BN_ * 16 * 1024);
  double* Pbuf = (double*)alloc((size_t)256 * 2048 * 2);
  double* Qbuf = (double*)alloc((size_t)256 * 2048 * 2);
  double* Fb   = (double*)alloc((size_t)1024 * 64 * 2);
  double* Qb   = (double*)alloc((size_t)1024 * 64 * 2);
  float*  scale= alloc(256);
  float*  shift= alloc(256);
  float*  sc5  = alloc(1024);
  float*  sh5  = alloc(1024);
  int*    idx  = (int*)alloc((size_t)TOTP * KNB);

  k_transpose<<<32, 256, 0, stream>>>(x, P0);

  struct L { const float* base; int lda, C, O, colout; const float* W; const float* g; const float* b; };
  L Ls[4] = {
    {P0,      3,   3,   64,  0,   W1, g1, b1},
    {F,       512, 64,  64,  64,  W2, g2, b2},
    {F + 64,  512, 64,  128, 128, W3, g3, b3},
    {F + 128, 512, 128, 256, 256, W4, g4, b4},
  };

  for (int l = 0; l < 4; ++l) {
    const L& a = Ls[l];
    k_sqnorm<<<32, 256, 0, stream>>>(a.base, a.lda, a.C, xx);
    if (l == 0) {
      k_topk3<<<dim3(512, BN_), 256, 0, stream>>>(P0, xx, idx);
    } else {
      k_gram64<<<dim3(528, 1, BN_), 256, 0, stream>>>(a.base, a.lda, a.C, G4);
      k_topk<<<dim3(512, BN_), 256, 0, stream>>>(G4, xx, idx);
    }
    int twoO = 2 * a.O;
    k_gemm64<<<dim3(twoO / 64, TOTP / 64), 256, 0, stream>>>(
        a.base, a.lda, a.C, a.W, 1, a.O, 2 * a.C, YS, twoO);
    k_gather<<<TOTP / 4, 256, 0, stream>>>(YS, twoO, a.O, idx, a.g, hsel, Pbuf, Qbuf);
    k_redstats<<<a.O, 256, 0, stream>>>(Pbuf, Qbuf, a.g, a.b, (float)(BN_ * NPTS * KNB),
                                        scale, shift);
    k_apply<<<TOTP * a.O / 256, 256, 0, stream>>>(hsel, scale, shift, F + a.colout, a.O);
  }

  // final: PF = F(8192x512) * W5^T(512x1024) via split-bf16 3-pass MFMA
  // pre-swizzled hi/lo tiles live in the dead YS/hsel region of U
  u16* FhT = (u16*)U;                       // 8192x512 -> 1024 tiles * 8KB
  u16* FlT = FhT + (size_t)4194304;
  u16* WhT = FlT + (size_t)4194304;         // 1024x512 -> 128 tiles * 8KB
  u16* WlT = WhT + (size_t)524288;
  k_split_swz<<<2048, 256, 0, stream>>>(F, FhT, FlT);
  k_split_swz<<<256, 256, 0, stream>>>(W5, WhT, WlT);
  k_gemm_mfma<<<dim3(8, 64), 256, 0, stream>>>(FhT, FlT, WhT, WlT, PF);

  k_fstats<<<dim3(64, 4), 256, 0, stream>>>(PF, Fb, Qb);
  k_red5<<<1024, 64, 0, stream>>>(Fb, Qb, g5, b5, sc5, sh5);

  float* out0 = (float*)d_out;
  float* gout = out0 + (size_t)BN_ * 1024 * 128;
  k_out0<<<dim3(16, 2, BN_), 256, 0, stream>>>(PF, sc5, sh5, out0);
  k_gmax<<<dim3(4, 16, BN_), 256, 0, stream>>>(PF, sc5, sh5, tmpmax);
  k_gdup<<<dim3(16, BN_), 256, 0, stream>>>(tmpmax, gout);
}